// Round 2
// baseline (1053.926 us; speedup 1.0000x reference)
//
#include <hip/hip_runtime.h>
#include <math.h>

namespace {

constexpr int Bn  = 8;
constexpr int Nn  = 500;
constexpr int Qn  = 25;
constexpr int ENC = 512;
constexpr int DIN = 300;
constexpr int NCn = 70;
constexpr int NETn = 3;

__device__ __forceinline__ float sigmoidf_(float x) { return 1.0f / (1.0f + expf(-x)); }

__device__ __forceinline__ float rowmask_of(int row, const int* __restrict__ lens) {
    int b = row / Nn;
    int i = row - b * Nn;
    return (i < lens[b]) ? 1.0f : 0.0f;
}

// ---------------------------------------------------------------------------
// A_sum[b,i,j] = sum_e adj[b,e,i,j]
__global__ __launch_bounds__(256) void sum_adj_k(const float* __restrict__ adj,
                                                 float* __restrict__ Asum) {
    size_t i = (size_t)blockIdx.x * 256 + threadIdx.x;
    constexpr size_t NN = (size_t)Nn * Nn;
    if (i >= (size_t)Bn * NN) return;
    size_t b = i / NN, r = i - b * NN;
    const float* base = adj + (b * NETn) * NN + r;
    Asum[i] = base[0] + base[NN] + base[2 * NN];
}

// ---------------------------------------------------------------------------
// 128x64 tile, BK=16, 8x4 per thread SGEMM: C = epi(A @ W + bias).
// Thread map: tm=t>>4 (8 rows each), tn=t&15 (4 cols each).
// Wave LDS pattern: As[kk][tm*8] broadcast (free), Ws[kk][tn*4] 2-way (free).
// EPI 0: tv=tanh(v); C=tv; C2=tv*rowmask   EPI 1: C=v   EPI 2: C=v*rowmask
template <int EPI>
__global__ __launch_bounds__(256) void sgemm128_k(const float* __restrict__ A,
                                                  const float* __restrict__ W,
                                                  const float* __restrict__ bias,
                                                  float* __restrict__ C,
                                                  float* __restrict__ C2,
                                                  int M, int N, int K,
                                                  const int* __restrict__ lens) {
    __shared__ float As[16][132];
    __shared__ float Ws[16][64];
    int t = threadIdx.x;
    int m0 = blockIdx.x * 128;
    int n0 = blockIdx.y * 64;
    int tm = t >> 4, tn = t & 15;
    int la_r = t >> 1;        // 0..127
    int la_k = (t & 1) * 8;   // 0 or 8
    int lw_r = t >> 4;        // 0..15
    int lw_n = (t & 15) * 4;

    float acc[8][4] = {};
    int ktiles = (K + 15) >> 4;
    for (int kt = 0; kt < ktiles; ++kt) {
        int k0 = kt << 4;
        {   // A tile -> As[k][m] (transposed)
            int row = m0 + la_r;
            const float* Arow = A + (size_t)row * K;
#pragma unroll
            for (int h = 0; h < 2; ++h) {
                int kg = k0 + la_k + h * 4;
                float vx = 0.f, vy = 0.f, vz = 0.f, vw = 0.f;
                if (row < M) {
                    if (kg + 4 <= K) {
                        float4 v = *(const float4*)(Arow + kg);
                        vx = v.x; vy = v.y; vz = v.z; vw = v.w;
                    } else {
                        if (kg + 0 < K) vx = Arow[kg + 0];
                        if (kg + 1 < K) vy = Arow[kg + 1];
                        if (kg + 2 < K) vz = Arow[kg + 2];
                        if (kg + 3 < K) vw = Arow[kg + 3];
                    }
                }
                int kb = la_k + h * 4;
                As[kb + 0][la_r] = vx; As[kb + 1][la_r] = vy;
                As[kb + 2][la_r] = vz; As[kb + 3][la_r] = vw;
            }
        }
        {   // W tile
            int kr = k0 + lw_r;
            float4 v = make_float4(0.f, 0.f, 0.f, 0.f);
            if (kr < K) v = *(const float4*)(W + (size_t)kr * N + n0 + lw_n);
            *(float4*)&Ws[lw_r][lw_n] = v;
        }
        __syncthreads();
#pragma unroll
        for (int kk = 0; kk < 16; ++kk) {
            float4 a0 = *(const float4*)&As[kk][tm * 8];
            float4 a1 = *(const float4*)&As[kk][tm * 8 + 4];
            float4 bv = *(const float4*)&Ws[kk][tn * 4];
            float a_[8] = {a0.x, a0.y, a0.z, a0.w, a1.x, a1.y, a1.z, a1.w};
            float b_[4] = {bv.x, bv.y, bv.z, bv.w};
#pragma unroll
            for (int i = 0; i < 8; ++i)
#pragma unroll
                for (int j = 0; j < 4; ++j) acc[i][j] = fmaf(a_[i], b_[j], acc[i][j]);
        }
        __syncthreads();
    }
    float4 bs = *(const float4*)(bias + n0 + tn * 4);
    float b_[4] = {bs.x, bs.y, bs.z, bs.w};
    for (int i = 0; i < 8; ++i) {
        int row = m0 + tm * 8 + i;
        if (row >= M) break;
        float rm = (EPI != 1) ? rowmask_of(row, lens) : 1.0f;
        size_t off = (size_t)row * N + n0 + tn * 4;
        float o[4];
#pragma unroll
        for (int j = 0; j < 4; ++j) {
            float v = acc[i][j] + b_[j];
            if (EPI == 0) o[j] = tanhf(v);
            else if (EPI == 1) o[j] = v;
            else o[j] = v * rm;
        }
        *(float4*)(C + off) = make_float4(o[0], o[1], o[2], o[3]);
        if (EPI == 0) {
            *(float4*)(C2 + off) = make_float4(o[0] * rm, o[1] * rm, o[2] * rm, o[3] * rm);
        }
    }
}

// ---------------------------------------------------------------------------
// update[b] = Asum[b] (500x500) @ hm[b] (500x512) + hm[b].  128x64 tile.
__global__ __launch_bounds__(256) void bgemm_update128_k(const float* __restrict__ Asum,
                                                         const float* __restrict__ hm,
                                                         float* __restrict__ upd) {
    __shared__ float As[16][132];
    __shared__ float Ws[16][64];
    int b = blockIdx.z;
    const float* A = Asum + (size_t)b * Nn * Nn;
    const float* W = hm + (size_t)b * Nn * ENC;
    int t = threadIdx.x;
    int m0 = blockIdx.x * 128;
    int n0 = blockIdx.y * 64;
    int tm = t >> 4, tn = t & 15;
    int la_r = t >> 1;
    int la_k = (t & 1) * 8;
    int lw_r = t >> 4;
    int lw_n = (t & 15) * 4;
    constexpr int M = Nn, N = ENC, K = Nn;

    float acc[8][4] = {};
    for (int kt = 0; kt < 32; ++kt) {   // ceil(500/16)=32
        int k0 = kt << 4;
        {
            int row = m0 + la_r;
            const float* Arow = A + (size_t)row * K;
#pragma unroll
            for (int h = 0; h < 2; ++h) {
                int kg = k0 + la_k + h * 4;
                float vx = 0.f, vy = 0.f, vz = 0.f, vw = 0.f;
                if (row < M && kg + 4 <= K) {
                    float4 v = *(const float4*)(Arow + kg);
                    vx = v.x; vy = v.y; vz = v.z; vw = v.w;
                }
                int kb = la_k + h * 4;
                As[kb + 0][la_r] = vx; As[kb + 1][la_r] = vy;
                As[kb + 2][la_r] = vz; As[kb + 3][la_r] = vw;
            }
        }
        {
            int kr = k0 + lw_r;
            float4 v = make_float4(0.f, 0.f, 0.f, 0.f);
            if (kr < K) v = *(const float4*)(W + (size_t)kr * N + n0 + lw_n);
            *(float4*)&Ws[lw_r][lw_n] = v;
        }
        __syncthreads();
#pragma unroll
        for (int kk = 0; kk < 16; ++kk) {
            float4 a0 = *(const float4*)&As[kk][tm * 8];
            float4 a1 = *(const float4*)&As[kk][tm * 8 + 4];
            float4 bv = *(const float4*)&Ws[kk][tn * 4];
            float a_[8] = {a0.x, a0.y, a0.z, a0.w, a1.x, a1.y, a1.z, a1.w};
            float b_[4] = {bv.x, bv.y, bv.z, bv.w};
#pragma unroll
            for (int i = 0; i < 8; ++i)
#pragma unroll
                for (int j = 0; j < 4; ++j) acc[i][j] = fmaf(a_[i], b_[j], acc[i][j]);
        }
        __syncthreads();
    }
    for (int i = 0; i < 8; ++i) {
        int row = m0 + tm * 8 + i;
        if (row >= M) break;
        size_t soff = (size_t)row * N + n0 + tn * 4;
        float4 h4 = *(const float4*)(W + soff);
        float4 o = make_float4(acc[i][0] + h4.x, acc[i][1] + h4.y,
                               acc[i][2] + h4.z, acc[i][3] + h4.w);
        *(float4*)(upd + (size_t)b * Nn * ENC + soff) = o;
    }
}

// ---------------------------------------------------------------------------
// att = sigmoid([upd|lh] @ Wc + bc)*rowmask; lh_out = att*tanh(upd)+(1-att)*lh
__global__ __launch_bounds__(256) void gemm_att128_k(const float* __restrict__ upd,
                                                     const float* __restrict__ lh,
                                                     const float* __restrict__ Wc,
                                                     const float* __restrict__ bc,
                                                     float* __restrict__ lh_out,
                                                     const int* __restrict__ lens) {
    __shared__ float As[16][132];
    __shared__ float Ws[16][64];
    int t = threadIdx.x;
    int m0 = blockIdx.x * 128;
    int n0 = blockIdx.y * 64;
    int tm = t >> 4, tn = t & 15;
    int la_r = t >> 1;
    int la_k = (t & 1) * 8;
    int lw_r = t >> 4;
    int lw_n = (t & 15) * 4;
    constexpr int M = Bn * Nn, N = ENC, K = 2 * ENC;

    float acc[8][4] = {};
    for (int kt = 0; kt < K / 16; ++kt) {
        int k0 = kt << 4;
        {
            int row = m0 + la_r;
#pragma unroll
            for (int h = 0; h < 2; ++h) {
                int kg = k0 + la_k + h * 4;
                float4 v = make_float4(0.f, 0.f, 0.f, 0.f);
                if (row < M) {
                    const float* src = (kg < ENC) ? (upd + (size_t)row * ENC + kg)
                                                  : (lh + (size_t)row * ENC + (kg - ENC));
                    v = *(const float4*)src;
                }
                int kb = la_k + h * 4;
                As[kb + 0][la_r] = v.x; As[kb + 1][la_r] = v.y;
                As[kb + 2][la_r] = v.z; As[kb + 3][la_r] = v.w;
            }
        }
        {
            int kr = k0 + lw_r;
            *(float4*)&Ws[lw_r][lw_n] = *(const float4*)(Wc + (size_t)kr * N + n0 + lw_n);
        }
        __syncthreads();
#pragma unroll
        for (int kk = 0; kk < 16; ++kk) {
            float4 a0 = *(const float4*)&As[kk][tm * 8];
            float4 a1 = *(const float4*)&As[kk][tm * 8 + 4];
            float4 bv = *(const float4*)&Ws[kk][tn * 4];
            float a_[8] = {a0.x, a0.y, a0.z, a0.w, a1.x, a1.y, a1.z, a1.w};
            float b_[4] = {bv.x, bv.y, bv.z, bv.w};
#pragma unroll
            for (int i = 0; i < 8; ++i)
#pragma unroll
                for (int j = 0; j < 4; ++j) acc[i][j] = fmaf(a_[i], b_[j], acc[i][j]);
        }
        __syncthreads();
    }
    float4 bs = *(const float4*)(bc + n0 + tn * 4);
    float bb[4] = {bs.x, bs.y, bs.z, bs.w};
    for (int i = 0; i < 8; ++i) {
        int row = m0 + tm * 8 + i;
        if (row >= M) break;
        float rm = rowmask_of(row, lens);
        size_t off = (size_t)row * ENC + n0 + tn * 4;
        float4 u4 = *(const float4*)(upd + off);
        float4 l4 = *(const float4*)(lh + off);
        float u_[4] = {u4.x, u4.y, u4.z, u4.w};
        float l_[4] = {l4.x, l4.y, l4.z, l4.w};
        float o[4];
#pragma unroll
        for (int j = 0; j < 4; ++j) {
            float a = sigmoidf_(acc[i][j] + bb[j]) * rm;
            o[j] = a * tanhf(u_[j]) + (1.0f - a) * l_[j];
        }
        *(float4*)(lh_out + off) = make_float4(o[0], o[1], o[2], o[3]);
    }
}

// ---------------------------------------------------------------------------
// Fused: sim -> softmax over q -> nodes2query; also rowmax (max over q) per node.
__global__ __launch_bounds__(256) void sim_fused_k(const float* __restrict__ lh,
                                                   const float* __restrict__ qc,
                                                   const float* __restrict__ wa,
                                                   float* __restrict__ n2q,
                                                   float* __restrict__ rowmax) {
    __shared__ float qcs[Qn * ENC];  // 51.2 KB
    __shared__ float qdot[Qn];
    int b = blockIdx.x;
    int t = threadIdx.x;
    const float* qcb = qc + (size_t)b * Qn * ENC;
    for (int i = t * 4; i < Qn * ENC; i += 256 * 4) *(float4*)&qcs[i] = *(const float4*)&qcb[i];
    __syncthreads();
    int wave = t >> 6, lane = t & 63;
    for (int q = wave; q < Qn; q += 4) {
        float p = 0.f;
        for (int d = lane; d < ENC; d += 64) p += qcs[q * ENC + d] * wa[ENC + d];
        for (int off = 32; off; off >>= 1) p += __shfl_xor(p, off, 64);
        if (lane == 0) qdot[q] = p;
    }
    __syncthreads();

    int nstart = blockIdx.y * 32;
    int nend = min(Nn, nstart + 32);
    for (int n = nstart + wave; n < nend; n += 4) {
        const float* lrow = lh + ((size_t)b * Nn + n) * ENC;
        float lvs[8];
        float ndot = 0.f;
#pragma unroll
        for (int it = 0; it < 8; ++it) {
            int d = lane + it * 64;
            float lv = lrow[d];
            ndot += lv * wa[d];
            lvs[it] = lv * wa[2 * ENC + d];
        }
        for (int off = 32; off; off >>= 1) ndot += __shfl_xor(ndot, off, 64);
        float s[Qn];
        for (int q = 0; q < Qn; ++q) {
            float p = 0.f;
#pragma unroll
            for (int it = 0; it < 8; ++it) p += lvs[it] * qcs[q * ENC + lane + it * 64];
            for (int off = 32; off; off >>= 1) p += __shfl_xor(p, off, 64);
            s[q] = p + ndot + qdot[q];
        }
        float m = s[0];
        for (int q = 1; q < Qn; ++q) m = fmaxf(m, s[q]);
        float sum = 0.f;
        for (int q = 0; q < Qn; ++q) { s[q] = expf(s[q] - m); sum += s[q]; }
        float inv = 1.0f / sum;
#pragma unroll
        for (int it = 0; it < 8; ++it) {
            int d = lane + it * 64;
            float o = 0.f;
            for (int q = 0; q < Qn; ++q) o += s[q] * qcs[q * ENC + d];
            n2q[((size_t)b * Nn + n) * ENC + d] = o * inv;
        }
        if (lane == 0) rowmax[b * Nn + n] = m;
    }
}

// ---------------------------------------------------------------------------
__global__ __launch_bounds__(512) void bvec_k(const float* __restrict__ rowmax,
                                              float* __restrict__ bvec) {
    __shared__ float red[8];
    int b = blockIdx.x, t = threadIdx.x;
    float v = (t < Nn) ? rowmax[b * Nn + t] : -INFINITY;
    float m = v;
    for (int off = 32; off; off >>= 1) m = fmaxf(m, __shfl_xor(m, off, 64));
    if ((t & 63) == 0) red[t >> 6] = m;
    __syncthreads();
    float bm = red[0];
    for (int i = 1; i < 8; ++i) bm = fmaxf(bm, red[i]);
    float e = (t < Nn) ? expf(v - bm) : 0.0f;
    float ssum = e;
    for (int off = 32; off; off >>= 1) ssum += __shfl_xor(ssum, off, 64);
    __syncthreads();
    if ((t & 63) == 0) red[t >> 6] = ssum;
    __syncthreads();
    float tot = 0.f;
    for (int i = 0; i < 8; ++i) tot += red[i];
    if (t < Nn) bvec[b * Nn + t] = e / tot;
}

// ---------------------------------------------------------------------------
__global__ __launch_bounds__(256) void q2n_k(const float* __restrict__ bvec,
                                             const float* __restrict__ nc,
                                             float* __restrict__ q2n) {
    int b = blockIdx.x;
    int d = blockIdx.y * 256 + threadIdx.x;
    const float* ncb = nc + (size_t)b * Nn * ENC;
    float acc = 0.f;
    for (int n = 0; n < Nn; ++n) acc = fmaf(bvec[b * Nn + n], ncb[(size_t)n * ENC + d], acc);
    q2n[b * ENC + d] = acc;
}

// ---------------------------------------------------------------------------
// Split-K partial of g @ W1: seg = blockIdx.y in [0,8), K-range seg*256..+256.
// g = [nc | n2q | nc*n2q | nc*q2n]; each seg lies inside one 512-wide part.
// 64 rows x 128 hidden per block; thread map: tmr=t&15 rows(4), tnc=t>>4 cols(8).
// Wave LDS: As[kk][tmr*4] 2-way (free), W1s[kk][tnc*8] broadcast (free).
__global__ __launch_bounds__(256) void final_part_k(const float* __restrict__ nc,
                                                    const float* __restrict__ n2q,
                                                    const float* __restrict__ q2n,
                                                    const float* __restrict__ W1p,
                                                    float* __restrict__ part) {
    __shared__ float As[16][68];
    __shared__ float W1s[16][128];
    int t = threadIdx.x;
    int m0 = blockIdx.x * 64;
    int seg = blockIdx.y;          // 0..7
    int p = seg >> 1;
    int dbase = (seg & 1) * 256;
    int tmr = t & 15;
    int tnc = t >> 4;
    int la_r = t >> 2;             // 0..63
    int la_k = (t & 3) * 4;
    constexpr int M = Bn * Nn;

    float acc[4][8] = {};
    for (int kt = 0; kt < 16; ++kt) {
        int k0 = kt << 4;
        {
            int row = m0 + la_r;
            int d = dbase + k0 + la_k;
            float4 v = make_float4(0.f, 0.f, 0.f, 0.f);
            if (row < M) {
                size_t off = (size_t)row * ENC + d;
                if (p == 0) v = *(const float4*)(nc + off);
                else if (p == 1) v = *(const float4*)(n2q + off);
                else if (p == 2) {
                    float4 a = *(const float4*)(nc + off);
                    float4 c = *(const float4*)(n2q + off);
                    v = make_float4(a.x * c.x, a.y * c.y, a.z * c.z, a.w * c.w);
                } else {
                    int bidx = row / Nn;
                    float4 a = *(const float4*)(nc + off);
                    float4 qv = *(const float4*)(q2n + (size_t)bidx * ENC + d);
                    v = make_float4(a.x * qv.x, a.y * qv.y, a.z * qv.z, a.w * qv.w);
                }
            }
            As[la_k + 0][la_r] = v.x; As[la_k + 1][la_r] = v.y;
            As[la_k + 2][la_r] = v.z; As[la_k + 3][la_r] = v.w;
        }
#pragma unroll
        for (int r = 0; r < 2; ++r) {
            int idx = t + r * 256;
            int kr = idx >> 5;
            int nq = (idx & 31) * 4;
            *(float4*)&W1s[kr][nq] =
                *(const float4*)(W1p + (size_t)(seg * 256 + k0 + kr) * 128 + nq);
        }
        __syncthreads();
#pragma unroll
        for (int kk = 0; kk < 16; ++kk) {
            float4 av = *(const float4*)&As[kk][tmr * 4];
            float4 b0 = *(const float4*)&W1s[kk][tnc * 8];
            float4 b1v = *(const float4*)&W1s[kk][tnc * 8 + 4];
            float a_[4] = {av.x, av.y, av.z, av.w};
            float b_[8] = {b0.x, b0.y, b0.z, b0.w, b1v.x, b1v.y, b1v.z, b1v.w};
#pragma unroll
            for (int i = 0; i < 4; ++i)
#pragma unroll
                for (int j = 0; j < 8; ++j) acc[i][j] = fmaf(a_[i], b_[j], acc[i][j]);
        }
        __syncthreads();
    }
    for (int i = 0; i < 4; ++i) {
        int row = m0 + tmr * 4 + i;
        if (row >= M) break;
        float* dst = part + ((size_t)seg * M + row) * 128 + tnc * 8;
        *(float4*)dst = make_float4(acc[i][0], acc[i][1], acc[i][2], acc[i][3]);
        *(float4*)(dst + 4) = make_float4(acc[i][4], acc[i][5], acc[i][6], acc[i][7]);
    }
}

// ---------------------------------------------------------------------------
// raw[row] = b2 + sum_h tanh(sum_s part[s][row][h] + b1[h]) * W2[h]
__global__ __launch_bounds__(256) void final_reduce_k(const float* __restrict__ part,
                                                      const float* __restrict__ b1p,
                                                      const float* __restrict__ W2p,
                                                      const float* __restrict__ b2p,
                                                      float* __restrict__ raw) {
    constexpr int M = Bn * Nn;
    int wave = threadIdx.x >> 6, lane = threadIdx.x & 63;
    int row = blockIdx.x * 4 + wave;
    if (row >= M) return;
    float v0 = 0.f, v1 = 0.f;
#pragma unroll
    for (int s = 0; s < 8; ++s) {
        const float* pr = part + ((size_t)s * M + row) * 128;
        v0 += pr[lane];
        v1 += pr[lane + 64];
    }
    float p = tanhf(v0 + b1p[lane]) * W2p[lane] + tanhf(v1 + b1p[lane + 64]) * W2p[lane + 64];
    for (int off = 32; off; off >>= 1) p += __shfl_xor(p, off, 64);
    if (lane == 0) raw[row] = p + b2p[0];
}

// ---------------------------------------------------------------------------
__global__ __launch_bounds__(256) void predmax_k(const int* __restrict__ mask,
                                                 const float* __restrict__ raw,
                                                 float* __restrict__ out) {
    int idx = blockIdx.x * 4 + (threadIdx.x >> 6);
    int lane = threadIdx.x & 63;
    if (idx >= Bn * NCn) return;
    int b = idx / NCn, c = idx - b * NCn;
    const int* mrow = mask + ((size_t)b * NCn + c) * Nn;
    const float* rrow = raw + (size_t)b * Nn;
    float mx = -INFINITY;
    for (int n = lane; n < Nn; n += 64) {
        float v = mrow[n] ? rrow[n] : 0.0f;
        if (v == 0.0f) v = -1.0e6f;
        mx = fmaxf(mx, v);
    }
    for (int off = 32; off; off >>= 1) mx = fmaxf(mx, __shfl_xor(mx, off, 64));
    if (lane == 0) out[idx] = mx;
}

}  // namespace

extern "C" void kernel_launch(void* const* d_in, const int* in_sizes, int n_in,
                              void* d_out, int out_size, void* d_ws, size_t ws_size,
                              hipStream_t stream) {
    const float* nodes_glove  = (const float*)d_in[0];
    const float* query_glove  = (const float*)d_in[1];
    const float* adj          = (const float*)d_in[2];
    const int*   nodes_length = (const int*)d_in[3];
    const int*   maskp        = (const int*)d_in[4];
    const float* Wn = (const float*)d_in[5];
    const float* bn = (const float*)d_in[6];
    const float* Wq = (const float*)d_in[7];
    const float* bq = (const float*)d_in[8];
    const float* Wh = (const float*)d_in[9];
    const float* bh = (const float*)d_in[10];
    const float* Wc = (const float*)d_in[11];
    const float* bc = (const float*)d_in[12];
    const float* wa = (const float*)d_in[13];
    const float* W1 = (const float*)d_in[14];
    const float* b1 = (const float*)d_in[15];
    const float* W2 = (const float*)d_in[16];
    const float* b2 = (const float*)d_in[17];
    float* out = (float*)d_out;

    float* ws = (float*)d_ws;
    size_t off = 0;
    auto alloc = [&](size_t n) { float* p = ws + off; off += n; return p; };
    // Order matters: lh0 and upd must be ADJACENT (they become the 8-seg
    // split-K partial buffer, exactly 8*4000*128 = 4,096,000 floats).
    float* nc   = alloc((size_t)Bn * Nn * ENC);
    float* lh0  = alloc((size_t)Bn * Nn * ENC);
    float* upd  = alloc((size_t)Bn * Nn * ENC);
    float* lh1  = alloc((size_t)Bn * Nn * ENC);
    float* hm   = alloc((size_t)Bn * Nn * ENC);   // reused as n2q after hops
    float* Asum = alloc((size_t)Bn * Nn * Nn);
    float* qc   = alloc((size_t)Bn * Qn * ENC);
    float* rowmax = alloc(Bn * Nn);
    float* bvec   = alloc(Bn * Nn);
    float* q2n    = alloc(Bn * ENC);
    float* raw    = alloc(Bn * Nn);
    float* n2q  = hm;
    float* part = lh0;   // spans lh0 + upd

    constexpr int M = Bn * Nn;  // 4000

    {
        size_t tot = (size_t)Bn * Nn * Nn;
        sum_adj_k<<<dim3((unsigned)((tot + 255) / 256)), 256, 0, stream>>>(adj, Asum);
    }
    sgemm128_k<0><<<dim3((M + 127) / 128, ENC / 64), 256, 0, stream>>>(
        nodes_glove, Wn, bn, nc, lh0, M, ENC, DIN, nodes_length);
    sgemm128_k<1><<<dim3((Bn * Qn + 127) / 128, ENC / 64), 256, 0, stream>>>(
        query_glove, Wq, bq, qc, nullptr, Bn * Qn, ENC, DIN, nodes_length);

    // 3 hops; cur starts at lh0 so after 3 swaps cur==lh1, freeing lh0+upd.
    float* cur = lh0;
    float* nxt = lh1;
    for (int h = 0; h < 3; ++h) {
        sgemm128_k<2><<<dim3((M + 127) / 128, ENC / 64), 256, 0, stream>>>(
            cur, Wh, bh, hm, nullptr, M, ENC, ENC, nodes_length);
        bgemm_update128_k<<<dim3((Nn + 127) / 128, ENC / 64, Bn), 256, 0, stream>>>(
            Asum, hm, upd);
        gemm_att128_k<<<dim3((M + 127) / 128, ENC / 64), 256, 0, stream>>>(
            upd, cur, Wc, bc, nxt, nodes_length);
        float* tmp = cur; cur = nxt; nxt = tmp;
    }
    // cur == lh1 == final last_hop

    sim_fused_k<<<dim3(Bn, 16), 256, 0, stream>>>(cur, qc, wa, n2q, rowmax);
    bvec_k<<<dim3(Bn), 512, 0, stream>>>(rowmax, bvec);
    q2n_k<<<dim3(Bn, ENC / 256), 256, 0, stream>>>(bvec, nc, q2n);
    final_part_k<<<dim3((M + 63) / 64, 8), 256, 0, stream>>>(nc, n2q, q2n, W1, part);
    final_reduce_k<<<dim3((M + 3) / 4), 256, 0, stream>>>(part, b1, W2, b2, raw);
    predmax_k<<<dim3((Bn * NCn + 3) / 4), 256, 0, stream>>>(maskp, raw, out);
}

// Round 3
// 545.638 us; speedup vs baseline: 1.9315x; 1.9315x over previous
//
#include <hip/hip_runtime.h>
#include <math.h>
#include <stdint.h>

namespace {

constexpr int Bn  = 8;
constexpr int Nn  = 500;
constexpr int Qn  = 25;
constexpr int ENC = 512;
constexpr int DIN = 300;
constexpr int NCn = 70;
constexpr int NETn = 3;

typedef __attribute__((ext_vector_type(8))) short bf16x8_t;
typedef __attribute__((ext_vector_type(4))) float f32x4_t;

__device__ __forceinline__ unsigned short f2bf(float f) {
    unsigned int u = __builtin_bit_cast(unsigned int, f);
    u += 0x7fffu + ((u >> 16) & 1u);   // RNE
    return (unsigned short)(u >> 16);
}
__device__ __forceinline__ float bf2f(unsigned short h) {
    unsigned int u = ((unsigned int)h) << 16;
    return __builtin_bit_cast(float, u);
}
__device__ __forceinline__ float sigmoidf_(float x) { return 1.0f / (1.0f + expf(-x)); }

// ---------------------------------------------------------------------------
// Asum[b][i][j] = sum_e adj[b,e,i,j], fp32, j padded 500->512 with zeros.
// grid 4000 (b*500+i), block 128 (each thread 4 cols).
__global__ __launch_bounds__(128) void sum_adj_pad_k(const float* __restrict__ adj,
                                                     float* __restrict__ Asum) {
    int bi = blockIdx.x;
    int b = bi / Nn, i = bi - b * Nn;
    int j = threadIdx.x * 4;
    float4 s = make_float4(0.f, 0.f, 0.f, 0.f);
    if (j < Nn) {
#pragma unroll
        for (int e = 0; e < NETn; ++e) {
            const float* p = adj + (((size_t)(b * NETn + e) * Nn) + i) * Nn + j;
            float4 v = *(const float4*)p;
            s.x += v.x; s.y += v.y; s.z += v.z; s.w += v.w;
        }
    }
    *(float4*)(Asum + ((size_t)bi) * 512 + j) = s;
}

// ---------------------------------------------------------------------------
// Transpose + convert: in f32 [K][N] -> out bf16 [N][Kpad], zero-padded k>=K.
// block 256 (32x8), grid (N/32, Kpad/32).
__global__ __launch_bounds__(256) void tcvt_k(const float* __restrict__ in,
                                              unsigned short* __restrict__ out,
                                              int K, int N, int Kpad) {
    __shared__ float tile[32][33];
    int tx = threadIdx.x & 31, ty = threadIdx.x >> 5;
    int n0 = blockIdx.x * 32, k0 = blockIdx.y * 32;
#pragma unroll
    for (int r = 0; r < 4; ++r) {
        int k = k0 + ty * 4 + r;
        int n = n0 + tx;
        tile[ty * 4 + r][tx] = (k < K && n < N) ? in[(size_t)k * N + n] : 0.0f;
    }
    __syncthreads();
#pragma unroll
    for (int r = 0; r < 4; ++r) {
        int n = n0 + ty * 4 + r;
        int k = k0 + tx;
        if (n < N && k < Kpad) out[(size_t)n * Kpad + k] = f2bf(tile[tx][ty * 4 + r]);
    }
}

// ---------------------------------------------------------------------------
// MFMA core: 64x64 output tile, BK=32, 256 threads = 4 waves (2x2 of 32x32).
// A: fp32 row-major, converted to bf16 during staging (lda elems/row).
//    Optional A2 for k>=ksplit (concat inputs, same lda).
// Bt: bf16, B^T row-major [n][k] (ldb elems/row).
// LDS 16B-lines XOR-swizzled: line (row, p) holds k-chunk q = p ^ ((row>>1)&3)
// so both the linear ds_write_b128 and the frag ds_read_b128 are conflict-free.
__device__ __forceinline__ void mfma_core(
    const float* __restrict__ A, const float* __restrict__ A2, int lda, int ksplit,
    const unsigned short* __restrict__ Bt, int ldb,
    int m0, int n0, int K, int Mlim,
    unsigned short* As, unsigned short* Bts, f32x4_t acc[2][2]) {
    const int t = threadIdx.x;
    const int lane = t & 63;
    const int w = t >> 6;
    const int sm = t >> 2;          // staging row 0..63
    const int sp = t & 3;           // physical 16B line within row
    const int sq = sp ^ ((sm >> 1) & 3);  // logical k-chunk staged by this thread
    const bool rowok = (m0 + sm) < Mlim;
    const int wm = (w & 1) * 32, wn = (w >> 1) * 32;
    const int quad = lane >> 4, cidx = lane & 15;
    const int am0 = wm + cidx, am1 = wm + 16 + cidx;
    const int an0 = wn + cidx, an1 = wn + 16 + cidx;
    const unsigned short* ap0 = As + am0 * 32 + (quad ^ ((am0 >> 1) & 3)) * 8;
    const unsigned short* ap1 = As + am1 * 32 + (quad ^ ((am1 >> 1) & 3)) * 8;
    const unsigned short* bp0 = Bts + an0 * 32 + (quad ^ ((an0 >> 1) & 3)) * 8;
    const unsigned short* bp1 = Bts + an1 * 32 + (quad ^ ((an1 >> 1) & 3)) * 8;

    for (int k0 = 0; k0 < K; k0 += 32) {
        int kg = k0 + sq * 8;
        float4 f0 = make_float4(0.f, 0.f, 0.f, 0.f);
        float4 f1 = make_float4(0.f, 0.f, 0.f, 0.f);
        if (rowok) {
            const float* src;
            if (A2 != nullptr && kg >= ksplit)
                src = A2 + (size_t)(m0 + sm) * lda + (kg - ksplit);
            else
                src = A + (size_t)(m0 + sm) * lda + kg;
            f0 = *(const float4*)src;
            f1 = *(const float4*)(src + 4);
        }
        bf16x8_t bstage = *(const bf16x8_t*)(Bt + (size_t)(n0 + sm) * ldb + kg);
        bf16x8_t astage;
        astage[0] = (short)f2bf(f0.x); astage[1] = (short)f2bf(f0.y);
        astage[2] = (short)f2bf(f0.z); astage[3] = (short)f2bf(f0.w);
        astage[4] = (short)f2bf(f1.x); astage[5] = (short)f2bf(f1.y);
        astage[6] = (short)f2bf(f1.z); astage[7] = (short)f2bf(f1.w);
        __syncthreads();                       // protect prior iter's reads
        *(bf16x8_t*)(As + t * 8) = astage;     // linear 16B lines
        *(bf16x8_t*)(Bts + t * 8) = bstage;
        __syncthreads();
        bf16x8_t a0 = *(const bf16x8_t*)ap0;
        bf16x8_t a1 = *(const bf16x8_t*)ap1;
        bf16x8_t b0 = *(const bf16x8_t*)bp0;
        bf16x8_t b1 = *(const bf16x8_t*)bp1;
        acc[0][0] = __builtin_amdgcn_mfma_f32_16x16x32_bf16(a0, b0, acc[0][0], 0, 0, 0);
        acc[0][1] = __builtin_amdgcn_mfma_f32_16x16x32_bf16(a0, b1, acc[0][1], 0, 0, 0);
        acc[1][0] = __builtin_amdgcn_mfma_f32_16x16x32_bf16(a1, b0, acc[1][0], 0, 0, 0);
        acc[1][1] = __builtin_amdgcn_mfma_f32_16x16x32_bf16(a1, b1, acc[1][1], 0, 0, 0);
    }
}

#define EPI_SETUP                                         \
    int t = threadIdx.x, lane = t & 63, w = t >> 6;       \
    int wm = (w & 1) * 32, wn = (w >> 1) * 32;            \
    int quad = lane >> 4, cidx = lane & 15;               \
    (void)wm; (void)wn; (void)quad; (void)cidx;

// ---------------------------------------------------------------------------
// nc = tanh(ng@Wn + bn); lh0 = nc * rowmask
__global__ __launch_bounds__(256) void gemm_nc_k(const float* __restrict__ ng,
                                                 const unsigned short* __restrict__ WnT,
                                                 const float* __restrict__ bn,
                                                 const int* __restrict__ lens,
                                                 float* __restrict__ nc,
                                                 float* __restrict__ lh0) {
    __shared__ unsigned short As[2048], Bts[2048];
    f32x4_t z = {0.f, 0.f, 0.f, 0.f};
    f32x4_t acc[2][2] = {{z, z}, {z, z}};
    int m0 = blockIdx.x * 64, n0 = blockIdx.y * 64;
    mfma_core(ng, nullptr, DIN, 1 << 30, WnT, 320, m0, n0, 320, Bn * Nn, As, Bts, acc);
    EPI_SETUP
#pragma unroll
    for (int nj = 0; nj < 2; ++nj) {
        int col = n0 + wn + nj * 16 + cidx;
        float bias = bn[col];
#pragma unroll
        for (int mi = 0; mi < 2; ++mi) {
#pragma unroll
            for (int r = 0; r < 4; ++r) {
                int row = m0 + wm + mi * 16 + quad * 4 + r;
                if (row < Bn * Nn) {
                    float tv = tanhf(acc[mi][nj][r] + bias);
                    int b = row / Nn, i = row - b * Nn;
                    float rm = (i < lens[b]) ? 1.0f : 0.0f;
                    nc[(size_t)row * ENC + col] = tv;
                    lh0[(size_t)row * ENC + col] = tv * rm;
                }
            }
        }
    }
}

// ---------------------------------------------------------------------------
// qc = qg@Wq + bq   (M = 200)
__global__ __launch_bounds__(256) void gemm_qc_k(const float* __restrict__ qg,
                                                 const unsigned short* __restrict__ WqT,
                                                 const float* __restrict__ bq,
                                                 float* __restrict__ qc) {
    __shared__ unsigned short As[2048], Bts[2048];
    f32x4_t z = {0.f, 0.f, 0.f, 0.f};
    f32x4_t acc[2][2] = {{z, z}, {z, z}};
    int m0 = blockIdx.x * 64, n0 = blockIdx.y * 64;
    mfma_core(qg, nullptr, DIN, 1 << 30, WqT, 320, m0, n0, 320, Bn * Qn, As, Bts, acc);
    EPI_SETUP
#pragma unroll
    for (int nj = 0; nj < 2; ++nj) {
        int col = n0 + wn + nj * 16 + cidx;
        float bias = bq[col];
#pragma unroll
        for (int mi = 0; mi < 2; ++mi) {
#pragma unroll
            for (int r = 0; r < 4; ++r) {
                int row = m0 + wm + mi * 16 + quad * 4 + r;
                if (row < Bn * Qn) qc[(size_t)row * ENC + col] = acc[mi][nj][r] + bias;
            }
        }
    }
}

// ---------------------------------------------------------------------------
// hmT[b][n][i] = bf16( (lh@Wh + bh)[b*500+i][n] * rowmask )   (transposed store)
__global__ __launch_bounds__(256) void gemm_hm_k(const float* __restrict__ lh,
                                                 const unsigned short* __restrict__ WhT,
                                                 const float* __restrict__ bh,
                                                 const int* __restrict__ lens,
                                                 unsigned short* __restrict__ hmT) {
    __shared__ unsigned short As[2048], Bts[2048];
    f32x4_t z = {0.f, 0.f, 0.f, 0.f};
    f32x4_t acc[2][2] = {{z, z}, {z, z}};
    int m0 = blockIdx.x * 64, n0 = blockIdx.y * 64;
    mfma_core(lh, nullptr, ENC, 1 << 30, WhT, ENC, m0, n0, ENC, Bn * Nn, As, Bts, acc);
    EPI_SETUP
#pragma unroll
    for (int nj = 0; nj < 2; ++nj) {
        int col = n0 + wn + nj * 16 + cidx;
        float bias = bh[col];
#pragma unroll
        for (int mi = 0; mi < 2; ++mi) {
#pragma unroll
            for (int r = 0; r < 4; ++r) {
                int row = m0 + wm + mi * 16 + quad * 4 + r;
                if (row < Bn * Nn) {
                    int b = row / Nn, i = row - b * Nn;
                    float rm = (i < lens[b]) ? 1.0f : 0.0f;
                    float v = (acc[mi][nj][r] + bias) * rm;
                    hmT[((size_t)b * ENC + col) * 512 + i] = f2bf(v);
                }
            }
        }
    }
}

// ---------------------------------------------------------------------------
// upd[b*500+i][n] = (Asum[b] @ hm[b])[i][n] + hm[b][i][n]   (batched, z = b)
__global__ __launch_bounds__(256) void gemm_upd_k(const float* __restrict__ Asum,
                                                  const unsigned short* __restrict__ hmT,
                                                  float* __restrict__ upd) {
    __shared__ unsigned short As[2048], Bts[2048];
    f32x4_t z = {0.f, 0.f, 0.f, 0.f};
    f32x4_t acc[2][2] = {{z, z}, {z, z}};
    int b = blockIdx.z;
    const float* A = Asum + (size_t)b * Nn * 512;
    const unsigned short* BtH = hmT + (size_t)b * ENC * 512;
    int m0 = blockIdx.x * 64, n0 = blockIdx.y * 64;
    mfma_core(A, nullptr, 512, 1 << 30, BtH, 512, m0, n0, 512, 1 << 30, As, Bts, acc);
    EPI_SETUP
#pragma unroll
    for (int nj = 0; nj < 2; ++nj) {
        int col = n0 + wn + nj * 16 + cidx;
#pragma unroll
        for (int mi = 0; mi < 2; ++mi) {
#pragma unroll
            for (int r = 0; r < 4; ++r) {
                int i = m0 + wm + mi * 16 + quad * 4 + r;
                if (i < Nn) {
                    float hv = bf2f(hmT[((size_t)b * ENC + col) * 512 + i]);
                    upd[((size_t)(b * Nn + i)) * ENC + col] = acc[mi][nj][r] + hv;
                }
            }
        }
    }
}

// ---------------------------------------------------------------------------
// att = sigmoid([upd|lh]@Wc + bc)*rm; lh_out = att*tanh(upd) + (1-att)*lh
__global__ __launch_bounds__(256) void gemm_att_k(const float* __restrict__ upd,
                                                  const float* __restrict__ lh,
                                                  const unsigned short* __restrict__ WcT,
                                                  const float* __restrict__ bc,
                                                  const int* __restrict__ lens,
                                                  float* __restrict__ lh_out) {
    __shared__ unsigned short As[2048], Bts[2048];
    f32x4_t z = {0.f, 0.f, 0.f, 0.f};
    f32x4_t acc[2][2] = {{z, z}, {z, z}};
    int m0 = blockIdx.x * 64, n0 = blockIdx.y * 64;
    mfma_core(upd, lh, ENC, ENC, WcT, 2 * ENC, m0, n0, 2 * ENC, Bn * Nn, As, Bts, acc);
    EPI_SETUP
#pragma unroll
    for (int nj = 0; nj < 2; ++nj) {
        int col = n0 + wn + nj * 16 + cidx;
        float bias = bc[col];
#pragma unroll
        for (int mi = 0; mi < 2; ++mi) {
#pragma unroll
            for (int r = 0; r < 4; ++r) {
                int row = m0 + wm + mi * 16 + quad * 4 + r;
                if (row < Bn * Nn) {
                    int b = row / Nn, i = row - b * Nn;
                    float rm = (i < lens[b]) ? 1.0f : 0.0f;
                    float a = sigmoidf_(acc[mi][nj][r] + bias) * rm;
                    size_t off = (size_t)row * ENC + col;
                    lh_out[off] = a * tanhf(upd[off]) + (1.0f - a) * lh[off];
                }
            }
        }
    }
}

// ---------------------------------------------------------------------------
// Fused: sim -> softmax over q -> nodes2query; also rowmax per node.
__global__ __launch_bounds__(256) void sim_fused_k(const float* __restrict__ lh,
                                                   const float* __restrict__ qc,
                                                   const float* __restrict__ wa,
                                                   float* __restrict__ n2q,
                                                   float* __restrict__ rowmax) {
    __shared__ float qcs[Qn * ENC];
    __shared__ float qdot[Qn];
    int b = blockIdx.x;
    int t = threadIdx.x;
    const float* qcb = qc + (size_t)b * Qn * ENC;
    for (int i = t * 4; i < Qn * ENC; i += 256 * 4) *(float4*)&qcs[i] = *(const float4*)&qcb[i];
    __syncthreads();
    int wave = t >> 6, lane = t & 63;
    for (int q = wave; q < Qn; q += 4) {
        float p = 0.f;
        for (int d = lane; d < ENC; d += 64) p += qcs[q * ENC + d] * wa[ENC + d];
        for (int off = 32; off; off >>= 1) p += __shfl_xor(p, off, 64);
        if (lane == 0) qdot[q] = p;
    }
    __syncthreads();

    int nstart = blockIdx.y * 32;
    int nend = min(Nn, nstart + 32);
    for (int n = nstart + wave; n < nend; n += 4) {
        const float* lrow = lh + ((size_t)b * Nn + n) * ENC;
        float lvs[8];
        float ndot = 0.f;
#pragma unroll
        for (int it = 0; it < 8; ++it) {
            int d = lane + it * 64;
            float lv = lrow[d];
            ndot += lv * wa[d];
            lvs[it] = lv * wa[2 * ENC + d];
        }
        for (int off = 32; off; off >>= 1) ndot += __shfl_xor(ndot, off, 64);
        float s[Qn];
        for (int q = 0; q < Qn; ++q) {
            float p = 0.f;
#pragma unroll
            for (int it = 0; it < 8; ++it) p += lvs[it] * qcs[q * ENC + lane + it * 64];
            for (int off = 32; off; off >>= 1) p += __shfl_xor(p, off, 64);
            s[q] = p + ndot + qdot[q];
        }
        float m = s[0];
        for (int q = 1; q < Qn; ++q) m = fmaxf(m, s[q]);
        float sum = 0.f;
        for (int q = 0; q < Qn; ++q) { s[q] = expf(s[q] - m); sum += s[q]; }
        float inv = 1.0f / sum;
#pragma unroll
        for (int it = 0; it < 8; ++it) {
            int d = lane + it * 64;
            float o = 0.f;
            for (int q = 0; q < Qn; ++q) o += s[q] * qcs[q * ENC + d];
            n2q[((size_t)b * Nn + n) * ENC + d] = o * inv;
        }
        if (lane == 0) rowmax[b * Nn + n] = m;
    }
}

// ---------------------------------------------------------------------------
__global__ __launch_bounds__(512) void bvec_k(const float* __restrict__ rowmax,
                                              float* __restrict__ bvec) {
    __shared__ float red[8];
    int b = blockIdx.x, t = threadIdx.x;
    float v = (t < Nn) ? rowmax[b * Nn + t] : -INFINITY;
    float m = v;
    for (int off = 32; off; off >>= 1) m = fmaxf(m, __shfl_xor(m, off, 64));
    if ((t & 63) == 0) red[t >> 6] = m;
    __syncthreads();
    float bm = red[0];
    for (int i = 1; i < 8; ++i) bm = fmaxf(bm, red[i]);
    float e = (t < Nn) ? expf(v - bm) : 0.0f;
    float ssum = e;
    for (int off = 32; off; off >>= 1) ssum += __shfl_xor(ssum, off, 64);
    __syncthreads();
    if ((t & 63) == 0) red[t >> 6] = ssum;
    __syncthreads();
    float tot = 0.f;
    for (int i = 0; i < 8; ++i) tot += red[i];
    if (t < Nn) bvec[b * Nn + t] = e / tot;
}

// ---------------------------------------------------------------------------
__global__ __launch_bounds__(256) void q2n_k(const float* __restrict__ bvec,
                                             const float* __restrict__ nc,
                                             float* __restrict__ q2n) {
    int b = blockIdx.x;
    int d = blockIdx.y * 256 + threadIdx.x;
    const float* ncb = nc + (size_t)b * Nn * ENC;
    float acc = 0.f;
    for (int n = 0; n < Nn; ++n) acc = fmaf(bvec[b * Nn + n], ncb[(size_t)n * ENC + d], acc);
    q2n[b * ENC + d] = acc;
}

// ---------------------------------------------------------------------------
// Split-K partial of g @ W1: p = blockIdx.y in [0,4): exactly one 512-wide part
// of g = [nc | n2q | nc*n2q | nc*q2n].  64 rows x 128 hidden per block.
__global__ __launch_bounds__(256) void final_part_k(const float* __restrict__ nc,
                                                    const float* __restrict__ n2q,
                                                    const float* __restrict__ q2n,
                                                    const float* __restrict__ W1p,
                                                    float* __restrict__ part) {
    __shared__ float As[16][68];
    __shared__ float W1s[16][128];
    int t = threadIdx.x;
    int m0 = blockIdx.x * 64;
    int p = blockIdx.y;            // 0..3
    int tmr = t & 15;
    int tnc = t >> 4;
    int la_r = t >> 2;
    int la_k = (t & 3) * 4;
    constexpr int M = Bn * Nn;

    float acc[4][8] = {};
    for (int kt = 0; kt < 32; ++kt) {
        int k0 = kt << 4;
        {
            int row = m0 + la_r;
            int d = k0 + la_k;
            float4 v = make_float4(0.f, 0.f, 0.f, 0.f);
            if (row < M) {
                size_t off = (size_t)row * ENC + d;
                if (p == 0) v = *(const float4*)(nc + off);
                else if (p == 1) v = *(const float4*)(n2q + off);
                else if (p == 2) {
                    float4 a = *(const float4*)(nc + off);
                    float4 c = *(const float4*)(n2q + off);
                    v = make_float4(a.x * c.x, a.y * c.y, a.z * c.z, a.w * c.w);
                } else {
                    int bidx = row / Nn;
                    float4 a = *(const float4*)(nc + off);
                    float4 qv = *(const float4*)(q2n + (size_t)bidx * ENC + d);
                    v = make_float4(a.x * qv.x, a.y * qv.y, a.z * qv.z, a.w * qv.w);
                }
            }
            As[la_k + 0][la_r] = v.x; As[la_k + 1][la_r] = v.y;
            As[la_k + 2][la_r] = v.z; As[la_k + 3][la_r] = v.w;
        }
#pragma unroll
        for (int r = 0; r < 2; ++r) {
            int idx = t + r * 256;
            int kr = idx >> 5;
            int nq = (idx & 31) * 4;
            *(float4*)&W1s[kr][nq] =
                *(const float4*)(W1p + (size_t)(p * 512 + k0 + kr) * 128 + nq);
        }
        __syncthreads();
#pragma unroll
        for (int kk = 0; kk < 16; ++kk) {
            float4 av = *(const float4*)&As[kk][tmr * 4];
            float4 b0 = *(const float4*)&W1s[kk][tnc * 8];
            float4 b1v = *(const float4*)&W1s[kk][tnc * 8 + 4];
            float a_[4] = {av.x, av.y, av.z, av.w};
            float b_[8] = {b0.x, b0.y, b0.z, b0.w, b1v.x, b1v.y, b1v.z, b1v.w};
#pragma unroll
            for (int i = 0; i < 4; ++i)
#pragma unroll
                for (int j = 0; j < 8; ++j) acc[i][j] = fmaf(a_[i], b_[j], acc[i][j]);
        }
        __syncthreads();
    }
    for (int i = 0; i < 4; ++i) {
        int row = m0 + tmr * 4 + i;
        if (row >= M) break;
        float* dst = part + ((size_t)p * M + row) * 128 + tnc * 8;
        *(float4*)dst = make_float4(acc[i][0], acc[i][1], acc[i][2], acc[i][3]);
        *(float4*)(dst + 4) = make_float4(acc[i][4], acc[i][5], acc[i][6], acc[i][7]);
    }
}

// ---------------------------------------------------------------------------
__global__ __launch_bounds__(256) void final_reduce_k(const float* __restrict__ part,
                                                      const float* __restrict__ b1p,
                                                      const float* __restrict__ W2p,
                                                      const float* __restrict__ b2p,
                                                      float* __restrict__ raw) {
    constexpr int M = Bn * Nn;
    int wave = threadIdx.x >> 6, lane = threadIdx.x & 63;
    int row = blockIdx.x * 4 + wave;
    if (row >= M) return;
    float v0 = 0.f, v1 = 0.f;
#pragma unroll
    for (int s = 0; s < 4; ++s) {
        const float* pr = part + ((size_t)s * M + row) * 128;
        v0 += pr[lane];
        v1 += pr[lane + 64];
    }
    float p = tanhf(v0 + b1p[lane]) * W2p[lane] + tanhf(v1 + b1p[lane + 64]) * W2p[lane + 64];
    for (int off = 32; off; off >>= 1) p += __shfl_xor(p, off, 64);
    if (lane == 0) raw[row] = p + b2p[0];
}

// ---------------------------------------------------------------------------
__global__ __launch_bounds__(256) void predmax_k(const int* __restrict__ mask,
                                                 const float* __restrict__ raw,
                                                 float* __restrict__ out) {
    int idx = blockIdx.x * 4 + (threadIdx.x >> 6);
    int lane = threadIdx.x & 63;
    if (idx >= Bn * NCn) return;
    int b = idx / NCn, c = idx - b * NCn;
    const int* mrow = mask + ((size_t)b * NCn + c) * Nn;
    const float* rrow = raw + (size_t)b * Nn;
    float mx = -INFINITY;
    for (int n = lane; n < Nn; n += 64) {
        float v = mrow[n] ? rrow[n] : 0.0f;
        if (v == 0.0f) v = -1.0e6f;
        mx = fmaxf(mx, v);
    }
    for (int off = 32; off; off >>= 1) mx = fmaxf(mx, __shfl_xor(mx, off, 64));
    if (lane == 0) out[idx] = mx;
}

}  // namespace

extern "C" void kernel_launch(void* const* d_in, const int* in_sizes, int n_in,
                              void* d_out, int out_size, void* d_ws, size_t ws_size,
                              hipStream_t stream) {
    const float* nodes_glove  = (const float*)d_in[0];
    const float* query_glove  = (const float*)d_in[1];
    const float* adj          = (const float*)d_in[2];
    const int*   nodes_length = (const int*)d_in[3];
    const int*   maskp        = (const int*)d_in[4];
    const float* Wn = (const float*)d_in[5];
    const float* bn = (const float*)d_in[6];
    const float* Wq = (const float*)d_in[7];
    const float* bq = (const float*)d_in[8];
    const float* Wh = (const float*)d_in[9];
    const float* bh = (const float*)d_in[10];
    const float* Wc = (const float*)d_in[11];
    const float* bc = (const float*)d_in[12];
    const float* wa = (const float*)d_in[13];
    const float* W1 = (const float*)d_in[14];
    const float* b1 = (const float*)d_in[15];
    const float* W2 = (const float*)d_in[16];
    const float* b2 = (const float*)d_in[17];
    float* out = (float*)d_out;

    float* ws = (float*)d_ws;
    size_t off = 0;
    auto alloc = [&](size_t n) { float* p = ws + off; off += n; return p; };
    constexpr size_t ME = (size_t)Bn * Nn * ENC;   // 2,048,000
    float* nc   = alloc(ME);
    float* lh0  = alloc(ME);
    float* upd  = alloc(ME);          // reused as 4-seg split-K part buffer
    float* lh1  = alloc(ME);
    float* Asum = alloc(ME);          // [8][500][512] padded; reused as n2q
    float* qc   = alloc((size_t)Bn * Qn * ENC);
    float* rowmax = alloc(Bn * Nn);
    float* bvec   = alloc(Bn * Nn);
    float* q2n    = alloc(Bn * ENC);
    float* raw    = alloc(Bn * Nn);
    // bf16 buffers (allocated in float-words)
    unsigned short* hmT = (unsigned short*)alloc((size_t)Bn * ENC * 512 / 2);  // [8][512][512]
    unsigned short* WnT = (unsigned short*)alloc((size_t)ENC * 320 / 2);       // [512][320]
    unsigned short* WqT = (unsigned short*)alloc((size_t)ENC * 320 / 2);
    unsigned short* WhT = (unsigned short*)alloc((size_t)ENC * ENC / 2);       // [512][512]
    unsigned short* WcT = (unsigned short*)alloc((size_t)ENC * 2 * ENC / 2);   // [512][1024]
    alloc(16384);  // 64 KB tail pad: staging may over-read past last buffer
    float* n2q  = Asum;
    float* part = upd;

    constexpr int M = Bn * Nn;  // 4000

    sum_adj_pad_k<<<dim3(Bn * Nn), 128, 0, stream>>>(adj, Asum);
    tcvt_k<<<dim3(16, 10), 256, 0, stream>>>(Wn, WnT, DIN, ENC, 320);
    tcvt_k<<<dim3(16, 10), 256, 0, stream>>>(Wq, WqT, DIN, ENC, 320);
    tcvt_k<<<dim3(16, 16), 256, 0, stream>>>(Wh, WhT, ENC, ENC, ENC);
    tcvt_k<<<dim3(16, 32), 256, 0, stream>>>(Wc, WcT, 2 * ENC, ENC, 2 * ENC);

    gemm_nc_k<<<dim3((M + 63) / 64, 8), 256, 0, stream>>>(nodes_glove, WnT, bn,
                                                          nodes_length, nc, lh0);
    gemm_qc_k<<<dim3((Bn * Qn + 63) / 64, 8), 256, 0, stream>>>(query_glove, WqT, bq, qc);

    float* cur = lh0;
    float* nxt = lh1;
    for (int h = 0; h < 3; ++h) {
        gemm_hm_k<<<dim3((M + 63) / 64, 8), 256, 0, stream>>>(cur, WhT, bh,
                                                              nodes_length, hmT);
        gemm_upd_k<<<dim3(8, 8, Bn), 256, 0, stream>>>(Asum, hmT, upd);
        gemm_att_k<<<dim3((M + 63) / 64, 8), 256, 0, stream>>>(upd, cur, WcT, bc,
                                                               nodes_length, nxt);
        float* tmp = cur; cur = nxt; nxt = tmp;
    }
    // cur == lh1 == final last_hop; Asum & upd now free.

    sim_fused_k<<<dim3(Bn, 16), 256, 0, stream>>>(cur, qc, wa, n2q, rowmax);
    bvec_k<<<dim3(Bn), 512, 0, stream>>>(rowmax, bvec);
    q2n_k<<<dim3(Bn, ENC / 256), 256, 0, stream>>>(bvec, nc, q2n);
    final_part_k<<<dim3((M + 63) / 64, 4), 256, 0, stream>>>(nc, n2q, q2n, W1, part);
    final_reduce_k<<<dim3((M + 3) / 4), 256, 0, stream>>>(part, b1, W2, b2, raw);
    predmax_k<<<dim3((Bn * NCn + 3) / 4), 256, 0, stream>>>(maskp, raw, out);
}

// Round 4
// 489.393 us; speedup vs baseline: 2.1535x; 1.1149x over previous
//
#include <hip/hip_runtime.h>
#include <math.h>
#include <stdint.h>

namespace {

constexpr int Bn  = 8;
constexpr int Nn  = 500;
constexpr int Qn  = 25;
constexpr int ENC = 512;
constexpr int DIN = 300;
constexpr int NCn = 70;
constexpr int NETn = 3;

typedef __attribute__((ext_vector_type(8))) short bf16x8_t;
typedef __attribute__((ext_vector_type(4))) float f32x4_t;

__device__ __forceinline__ unsigned short f2bf(float f) {
    unsigned int u = __builtin_bit_cast(unsigned int, f);
    u += 0x7fffu + ((u >> 16) & 1u);   // RNE
    return (unsigned short)(u >> 16);
}
__device__ __forceinline__ float bf2f(unsigned short h) {
    unsigned int u = ((unsigned int)h) << 16;
    return __builtin_bit_cast(float, u);
}
__device__ __forceinline__ float sigmoidf_(float x) { return 1.0f / (1.0f + expf(-x)); }

// ---------------------------------------------------------------------------
// Asum[b][i][j] = sum_e adj[b,e,i,j], fp32, j padded 500->512 with zeros.
__global__ __launch_bounds__(128) void sum_adj_pad_k(const float* __restrict__ adj,
                                                     float* __restrict__ Asum) {
    int bi = blockIdx.x;
    int b = bi / Nn, i = bi - b * Nn;
    int j = threadIdx.x * 4;
    float4 s = make_float4(0.f, 0.f, 0.f, 0.f);
    if (j < Nn) {
#pragma unroll
        for (int e = 0; e < NETn; ++e) {
            const float* p = adj + (((size_t)(b * NETn + e) * Nn) + i) * Nn + j;
            float4 v = *(const float4*)p;
            s.x += v.x; s.y += v.y; s.z += v.z; s.w += v.w;
        }
    }
    *(float4*)(Asum + ((size_t)bi) * 512 + j) = s;
}

// ---------------------------------------------------------------------------
// Transpose + convert: in f32 [K][N] -> out bf16 [N][Kpad], zero-padded k>=K.
__global__ __launch_bounds__(256) void tcvt_k(const float* __restrict__ in,
                                              unsigned short* __restrict__ out,
                                              int K, int N, int Kpad) {
    __shared__ float tile[32][33];
    int tx = threadIdx.x & 31, ty = threadIdx.x >> 5;
    int n0 = blockIdx.x * 32, k0 = blockIdx.y * 32;
#pragma unroll
    for (int r = 0; r < 4; ++r) {
        int k = k0 + ty * 4 + r;
        int n = n0 + tx;
        tile[ty * 4 + r][tx] = (k < K && n < N) ? in[(size_t)k * N + n] : 0.0f;
    }
    __syncthreads();
#pragma unroll
    for (int r = 0; r < 4; ++r) {
        int n = n0 + ty * 4 + r;
        int k = k0 + tx;
        if (n < N && k < Kpad) out[(size_t)n * Kpad + k] = f2bf(tile[tx][ty * 4 + r]);
    }
}

// ---------------------------------------------------------------------------
// MFMA core: 64x64 output tile, BK=32, 256 threads = 4 waves (2x2 of 32x32),
// double-buffered LDS (one barrier per K-step).
// A: fp32 row-major, cvt to bf16 during staging. Optional A2 for k>=ksplit.
// Bt: bf16 B^T row-major [n][k].
// LDS 16B lines XOR-swizzled: both ds_write_b128 and ds_read_b128 conflict-free.
__device__ __forceinline__ void mfma_core(
    const float* __restrict__ A, const float* __restrict__ A2, int lda, int ksplit,
    const unsigned short* __restrict__ Bt, int ldb,
    int m0, int n0, int K, int Mlim,
    unsigned short* As, unsigned short* Bts, f32x4_t acc[2][2]) {
    const int t = threadIdx.x;
    const int lane = t & 63;
    const int w = t >> 6;
    const int sm = t >> 2;                 // staging row 0..63
    const int sp = t & 3;                  // physical 16B line within row
    const int sq = sp ^ ((sm >> 1) & 3);   // logical k-chunk staged
    const bool rowok = (m0 + sm) < Mlim;
    const int wm = (w & 1) * 32, wn = (w >> 1) * 32;
    const int quad = lane >> 4, cidx = lane & 15;
    const int am0 = wm + cidx, am1 = wm + 16 + cidx;
    const int an0 = wn + cidx, an1 = wn + 16 + cidx;
    const int apo0 = am0 * 32 + (quad ^ ((am0 >> 1) & 3)) * 8;
    const int apo1 = am1 * 32 + (quad ^ ((am1 >> 1) & 3)) * 8;
    const int bpo0 = an0 * 32 + (quad ^ ((an0 >> 1) & 3)) * 8;
    const int bpo1 = an1 * 32 + (quad ^ ((an1 >> 1) & 3)) * 8;

    bf16x8_t ast, bst;
    auto stage = [&](int k0) {
        int kg = k0 + sq * 8;
        float4 f0 = make_float4(0.f, 0.f, 0.f, 0.f);
        float4 f1 = make_float4(0.f, 0.f, 0.f, 0.f);
        if (rowok) {
            const float* src;
            if (A2 != nullptr && kg >= ksplit)
                src = A2 + (size_t)(m0 + sm) * lda + (kg - ksplit);
            else
                src = A + (size_t)(m0 + sm) * lda + kg;
            f0 = *(const float4*)src;
            f1 = *(const float4*)(src + 4);
        }
        bst = *(const bf16x8_t*)(Bt + (size_t)(n0 + sm) * ldb + kg);
        ast[0] = (short)f2bf(f0.x); ast[1] = (short)f2bf(f0.y);
        ast[2] = (short)f2bf(f0.z); ast[3] = (short)f2bf(f0.w);
        ast[4] = (short)f2bf(f1.x); ast[5] = (short)f2bf(f1.y);
        ast[6] = (short)f2bf(f1.z); ast[7] = (short)f2bf(f1.w);
    };

    const int ktot = K >> 5;
    stage(0);
    *(bf16x8_t*)(As + t * 8) = ast;
    *(bf16x8_t*)(Bts + t * 8) = bst;
    for (int kt = 0; kt < ktot; ++kt) {
        __syncthreads();
        const int cur = (kt & 1) * 2048;
        const bool more = (kt + 1) < ktot;
        if (more) stage((kt + 1) << 5);
        bf16x8_t a0 = *(const bf16x8_t*)(As + cur + apo0);
        bf16x8_t a1 = *(const bf16x8_t*)(As + cur + apo1);
        bf16x8_t b0 = *(const bf16x8_t*)(Bts + cur + bpo0);
        bf16x8_t b1 = *(const bf16x8_t*)(Bts + cur + bpo1);
        acc[0][0] = __builtin_amdgcn_mfma_f32_16x16x32_bf16(a0, b0, acc[0][0], 0, 0, 0);
        acc[0][1] = __builtin_amdgcn_mfma_f32_16x16x32_bf16(a0, b1, acc[0][1], 0, 0, 0);
        acc[1][0] = __builtin_amdgcn_mfma_f32_16x16x32_bf16(a1, b0, acc[1][0], 0, 0, 0);
        acc[1][1] = __builtin_amdgcn_mfma_f32_16x16x32_bf16(a1, b1, acc[1][1], 0, 0, 0);
        if (more) {
            const int nxt = ((kt + 1) & 1) * 2048;
            *(bf16x8_t*)(As + nxt + t * 8) = ast;
            *(bf16x8_t*)(Bts + nxt + t * 8) = bst;
        }
    }
}

#define EPI_SETUP                                         \
    int t = threadIdx.x, lane = t & 63, w = t >> 6;       \
    int wm = (w & 1) * 32, wn = (w >> 1) * 32;            \
    int quad = lane >> 4, cidx = lane & 15;               \
    (void)wm; (void)wn; (void)quad; (void)cidx;

// ---------------------------------------------------------------------------
__global__ __launch_bounds__(256) void gemm_nc_k(const float* __restrict__ ng,
                                                 const unsigned short* __restrict__ WnT,
                                                 const float* __restrict__ bn,
                                                 const int* __restrict__ lens,
                                                 float* __restrict__ nc,
                                                 float* __restrict__ lh0) {
    __shared__ unsigned short As[4096], Bts[4096];
    f32x4_t z = {0.f, 0.f, 0.f, 0.f};
    f32x4_t acc[2][2] = {{z, z}, {z, z}};
    int m0 = blockIdx.x * 64, n0 = blockIdx.y * 64;
    mfma_core(ng, nullptr, DIN, 1 << 30, WnT, 320, m0, n0, 320, Bn * Nn, As, Bts, acc);
    EPI_SETUP
#pragma unroll
    for (int nj = 0; nj < 2; ++nj) {
        int col = n0 + wn + nj * 16 + cidx;
        float bias = bn[col];
#pragma unroll
        for (int mi = 0; mi < 2; ++mi) {
#pragma unroll
            for (int r = 0; r < 4; ++r) {
                int row = m0 + wm + mi * 16 + quad * 4 + r;
                if (row < Bn * Nn) {
                    float tv = tanhf(acc[mi][nj][r] + bias);
                    int b = row / Nn, i = row - b * Nn;
                    float rm = (i < lens[b]) ? 1.0f : 0.0f;
                    nc[(size_t)row * ENC + col] = tv;
                    lh0[(size_t)row * ENC + col] = tv * rm;
                }
            }
        }
    }
}

// ---------------------------------------------------------------------------
__global__ __launch_bounds__(256) void gemm_qc_k(const float* __restrict__ qg,
                                                 const unsigned short* __restrict__ WqT,
                                                 const float* __restrict__ bq,
                                                 float* __restrict__ qc) {
    __shared__ unsigned short As[4096], Bts[4096];
    f32x4_t z = {0.f, 0.f, 0.f, 0.f};
    f32x4_t acc[2][2] = {{z, z}, {z, z}};
    int m0 = blockIdx.x * 64, n0 = blockIdx.y * 64;
    mfma_core(qg, nullptr, DIN, 1 << 30, WqT, 320, m0, n0, 320, Bn * Qn, As, Bts, acc);
    EPI_SETUP
#pragma unroll
    for (int nj = 0; nj < 2; ++nj) {
        int col = n0 + wn + nj * 16 + cidx;
        float bias = bq[col];
#pragma unroll
        for (int mi = 0; mi < 2; ++mi) {
#pragma unroll
            for (int r = 0; r < 4; ++r) {
                int row = m0 + wm + mi * 16 + quad * 4 + r;
                if (row < Bn * Qn) qc[(size_t)row * ENC + col] = acc[mi][nj][r] + bias;
            }
        }
    }
}

// ---------------------------------------------------------------------------
__global__ __launch_bounds__(256) void gemm_hm_k(const float* __restrict__ lh,
                                                 const unsigned short* __restrict__ WhT,
                                                 const float* __restrict__ bh,
                                                 const int* __restrict__ lens,
                                                 unsigned short* __restrict__ hmT) {
    __shared__ unsigned short As[4096], Bts[4096];
    f32x4_t z = {0.f, 0.f, 0.f, 0.f};
    f32x4_t acc[2][2] = {{z, z}, {z, z}};
    int m0 = blockIdx.x * 64, n0 = blockIdx.y * 64;
    mfma_core(lh, nullptr, ENC, 1 << 30, WhT, ENC, m0, n0, ENC, Bn * Nn, As, Bts, acc);
    EPI_SETUP
#pragma unroll
    for (int nj = 0; nj < 2; ++nj) {
        int col = n0 + wn + nj * 16 + cidx;
        float bias = bh[col];
#pragma unroll
        for (int mi = 0; mi < 2; ++mi) {
#pragma unroll
            for (int r = 0; r < 4; ++r) {
                int row = m0 + wm + mi * 16 + quad * 4 + r;
                if (row < Bn * Nn) {
                    int b = row / Nn, i = row - b * Nn;
                    float rm = (i < lens[b]) ? 1.0f : 0.0f;
                    float v = (acc[mi][nj][r] + bias) * rm;
                    hmT[((size_t)b * ENC + col) * 512 + i] = f2bf(v);
                }
            }
        }
    }
}

// ---------------------------------------------------------------------------
__global__ __launch_bounds__(256) void gemm_upd_k(const float* __restrict__ Asum,
                                                  const unsigned short* __restrict__ hmT,
                                                  float* __restrict__ upd) {
    __shared__ unsigned short As[4096], Bts[4096];
    f32x4_t z = {0.f, 0.f, 0.f, 0.f};
    f32x4_t acc[2][2] = {{z, z}, {z, z}};
    int b = blockIdx.z;
    const float* A = Asum + (size_t)b * Nn * 512;
    const unsigned short* BtH = hmT + (size_t)b * ENC * 512;
    int m0 = blockIdx.x * 64, n0 = blockIdx.y * 64;
    mfma_core(A, nullptr, 512, 1 << 30, BtH, 512, m0, n0, 512, 1 << 30, As, Bts, acc);
    EPI_SETUP
#pragma unroll
    for (int nj = 0; nj < 2; ++nj) {
        int col = n0 + wn + nj * 16 + cidx;
#pragma unroll
        for (int mi = 0; mi < 2; ++mi) {
#pragma unroll
            for (int r = 0; r < 4; ++r) {
                int i = m0 + wm + mi * 16 + quad * 4 + r;
                if (i < Nn) {
                    float hv = bf2f(hmT[((size_t)b * ENC + col) * 512 + i]);
                    upd[((size_t)(b * Nn + i)) * ENC + col] = acc[mi][nj][r] + hv;
                }
            }
        }
    }
}

// ---------------------------------------------------------------------------
__global__ __launch_bounds__(256) void gemm_att_k(const float* __restrict__ upd,
                                                  const float* __restrict__ lh,
                                                  const unsigned short* __restrict__ WcT,
                                                  const float* __restrict__ bc,
                                                  const int* __restrict__ lens,
                                                  float* __restrict__ lh_out) {
    __shared__ unsigned short As[4096], Bts[4096];
    f32x4_t z = {0.f, 0.f, 0.f, 0.f};
    f32x4_t acc[2][2] = {{z, z}, {z, z}};
    int m0 = blockIdx.x * 64, n0 = blockIdx.y * 64;
    mfma_core(upd, lh, ENC, ENC, WcT, 2 * ENC, m0, n0, 2 * ENC, Bn * Nn, As, Bts, acc);
    EPI_SETUP
#pragma unroll
    for (int nj = 0; nj < 2; ++nj) {
        int col = n0 + wn + nj * 16 + cidx;
        float bias = bc[col];
#pragma unroll
        for (int mi = 0; mi < 2; ++mi) {
#pragma unroll
            for (int r = 0; r < 4; ++r) {
                int row = m0 + wm + mi * 16 + quad * 4 + r;
                if (row < Bn * Nn) {
                    int b = row / Nn, i = row - b * Nn;
                    float rm = (i < lens[b]) ? 1.0f : 0.0f;
                    float a = sigmoidf_(acc[mi][nj][r] + bias) * rm;
                    size_t off = (size_t)row * ENC + col;
                    lh_out[off] = a * tanhf(upd[off]) + (1.0f - a) * lh[off];
                }
            }
        }
    }
}

// ---------------------------------------------------------------------------
// Fused sim -> softmax(q) -> nodes2query + rowmax.  One wave per n-row.
// Lane owns d in [8*lane, 8*lane+8). After per-q butterfly reductions every
// lane holds all 25 sims -> in-register softmax, no cross-lane phase 2.
// grid (B, 125), block 256 (4 waves = 4 rows).
__global__ __launch_bounds__(256) void sim_fused_k(const float* __restrict__ lh,
                                                   const float* __restrict__ qc,
                                                   const float* __restrict__ wa,
                                                   float* __restrict__ n2q,
                                                   float* __restrict__ rowmax) {
    __shared__ float qcs[Qn * ENC];   // 51.2 KB
    __shared__ float qdot[32];
    int b = blockIdx.x;
    int t = threadIdx.x;
    const float* qcb = qc + (size_t)b * Qn * ENC;
    for (int i = t * 4; i < Qn * ENC; i += 1024) *(float4*)&qcs[i] = *(const float4*)&qcb[i];
    __syncthreads();
    // qdot[q] = qc[q] . wa_q   (once per block; 8 lanes per q)
    {
        int q = t >> 3, j = t & 7;
        if (q < Qn) {
            float s = 0.f;
            for (int k = 0; k < 64; ++k) {
                int d = j + 8 * k;
                s += qcs[q * ENC + d] * wa[ENC + d];
            }
            s += __shfl_xor(s, 1, 64);
            s += __shfl_xor(s, 2, 64);
            s += __shfl_xor(s, 4, 64);
            if (j == 0) qdot[q] = s;
        }
    }
    __syncthreads();

    int wv = t >> 6, lane = t & 63;
    int n = blockIdx.y * 4 + wv;   // 125*4 = 500 exactly
    int d0 = lane * 8;
    const float* lrow = lh + ((size_t)b * Nn + n) * ENC;
    float4 la = *(const float4*)(lrow + d0);
    float4 lb = *(const float4*)(lrow + d0 + 4);
    float lv[8] = {la.x, la.y, la.z, la.w, lb.x, lb.y, lb.z, lb.w};
    float ndp = 0.f;
    float lvs[8];
#pragma unroll
    for (int j = 0; j < 8; ++j) {
        ndp += lv[j] * wa[d0 + j];
        lvs[j] = lv[j] * wa[2 * ENC + d0 + j];
    }
#pragma unroll
    for (int off = 32; off; off >>= 1) ndp += __shfl_xor(ndp, off, 64);

    float s_[Qn];
#pragma unroll
    for (int q = 0; q < Qn; ++q) {
        const float* qrow = qcs + q * ENC + d0;
        float4 qa = *(const float4*)qrow;
        float4 qb = *(const float4*)(qrow + 4);
        s_[q] = lvs[0] * qa.x + lvs[1] * qa.y + lvs[2] * qa.z + lvs[3] * qa.w +
                lvs[4] * qb.x + lvs[5] * qb.y + lvs[6] * qb.z + lvs[7] * qb.w;
    }
#pragma unroll
    for (int q = 0; q < Qn; ++q) {
#pragma unroll
        for (int off = 32; off; off >>= 1) s_[q] += __shfl_xor(s_[q], off, 64);
    }
    float mx = -INFINITY;
#pragma unroll
    for (int q = 0; q < Qn; ++q) {
        s_[q] += ndp + qdot[q];
        mx = fmaxf(mx, s_[q]);
    }
    float sum = 0.f;
#pragma unroll
    for (int q = 0; q < Qn; ++q) { s_[q] = expf(s_[q] - mx); sum += s_[q]; }
    float inv = 1.0f / sum;
    float o[8] = {};
#pragma unroll
    for (int q = 0; q < Qn; ++q) {
        const float* qrow = qcs + q * ENC + d0;
        float4 qa = *(const float4*)qrow;
        float4 qb = *(const float4*)(qrow + 4);
        float p = s_[q] * inv;
        o[0] += p * qa.x; o[1] += p * qa.y; o[2] += p * qa.z; o[3] += p * qa.w;
        o[4] += p * qb.x; o[5] += p * qb.y; o[6] += p * qb.z; o[7] += p * qb.w;
    }
    float* orow = n2q + ((size_t)b * Nn + n) * ENC + d0;
    *(float4*)orow = make_float4(o[0], o[1], o[2], o[3]);
    *(float4*)(orow + 4) = make_float4(o[4], o[5], o[6], o[7]);
    if (lane == 0) rowmax[b * Nn + n] = mx;
}

// ---------------------------------------------------------------------------
__global__ __launch_bounds__(512) void bvec_k(const float* __restrict__ rowmax,
                                              float* __restrict__ bvec) {
    __shared__ float red[8];
    int b = blockIdx.x, t = threadIdx.x;
    float v = (t < Nn) ? rowmax[b * Nn + t] : -INFINITY;
    float m = v;
    for (int off = 32; off; off >>= 1) m = fmaxf(m, __shfl_xor(m, off, 64));
    if ((t & 63) == 0) red[t >> 6] = m;
    __syncthreads();
    float bm = red[0];
    for (int i = 1; i < 8; ++i) bm = fmaxf(bm, red[i]);
    float e = (t < Nn) ? expf(v - bm) : 0.0f;
    float ssum = e;
    for (int off = 32; off; off >>= 1) ssum += __shfl_xor(ssum, off, 64);
    __syncthreads();
    if ((t & 63) == 0) red[t >> 6] = ssum;
    __syncthreads();
    float tot = 0.f;
    for (int i = 0; i < 8; ++i) tot += red[i];
    if (t < Nn) bvec[b * Nn + t] = e / tot;
}

// ---------------------------------------------------------------------------
__global__ __launch_bounds__(256) void q2n_k(const float* __restrict__ bvec,
                                             const float* __restrict__ nc,
                                             float* __restrict__ q2n) {
    int b = blockIdx.x;
    int d = blockIdx.y * 256 + threadIdx.x;
    const float* ncb = nc + (size_t)b * Nn * ENC;
    float acc = 0.f;
    for (int n = 0; n < Nn; ++n) acc = fmaf(bvec[b * Nn + n], ncb[(size_t)n * ENC + d], acc);
    q2n[b * ENC + d] = acc;
}

// ---------------------------------------------------------------------------
// Split-K partial of g @ W1: p = blockIdx.y in [0,4): one 512-wide part of
// g = [nc | n2q | nc*n2q | nc*q2n].  64 rows x 128 hidden per block.
__global__ __launch_bounds__(256) void final_part_k(const float* __restrict__ nc,
                                                    const float* __restrict__ n2q,
                                                    const float* __restrict__ q2n,
                                                    const float* __restrict__ W1p,
                                                    float* __restrict__ part) {
    __shared__ float As[16][68];
    __shared__ float W1s[16][128];
    int t = threadIdx.x;
    int m0 = blockIdx.x * 64;
    int p = blockIdx.y;            // 0..3
    int tmr = t & 15;
    int tnc = t >> 4;
    int la_r = t >> 2;
    int la_k = (t & 3) * 4;
    constexpr int M = Bn * Nn;

    float acc[4][8] = {};
    for (int kt = 0; kt < 32; ++kt) {
        int k0 = kt << 4;
        {
            int row = m0 + la_r;
            int d = k0 + la_k;
            float4 v = make_float4(0.f, 0.f, 0.f, 0.f);
            if (row < M) {
                size_t off = (size_t)row * ENC + d;
                if (p == 0) v = *(const float4*)(nc + off);
                else if (p == 1) v = *(const float4*)(n2q + off);
                else if (p == 2) {
                    float4 a = *(const float4*)(nc + off);
                    float4 c = *(const float4*)(n2q + off);
                    v = make_float4(a.x * c.x, a.y * c.y, a.z * c.z, a.w * c.w);
                } else {
                    int bidx = row / Nn;
                    float4 a = *(const float4*)(nc + off);
                    float4 qv = *(const float4*)(q2n + (size_t)bidx * ENC + d);
                    v = make_float4(a.x * qv.x, a.y * qv.y, a.z * qv.z, a.w * qv.w);
                }
            }
            As[la_k + 0][la_r] = v.x; As[la_k + 1][la_r] = v.y;
            As[la_k + 2][la_r] = v.z; As[la_k + 3][la_r] = v.w;
        }
#pragma unroll
        for (int r = 0; r < 2; ++r) {
            int idx = t + r * 256;
            int kr = idx >> 5;
            int nq = (idx & 31) * 4;
            *(float4*)&W1s[kr][nq] =
                *(const float4*)(W1p + (size_t)(p * 512 + k0 + kr) * 128 + nq);
        }
        __syncthreads();
#pragma unroll
        for (int kk = 0; kk < 16; ++kk) {
            float4 av = *(const float4*)&As[kk][tmr * 4];
            float4 b0 = *(const float4*)&W1s[kk][tnc * 8];
            float4 b1v = *(const float4*)&W1s[kk][tnc * 8 + 4];
            float a_[4] = {av.x, av.y, av.z, av.w};
            float b_[8] = {b0.x, b0.y, b0.z, b0.w, b1v.x, b1v.y, b1v.z, b1v.w};
#pragma unroll
            for (int i = 0; i < 4; ++i)
#pragma unroll
                for (int j = 0; j < 8; ++j) acc[i][j] = fmaf(a_[i], b_[j], acc[i][j]);
        }
        __syncthreads();
    }
    for (int i = 0; i < 4; ++i) {
        int row = m0 + tmr * 4 + i;
        if (row >= M) break;
        float* dst = part + ((size_t)p * M + row) * 128 + tnc * 8;
        *(float4*)dst = make_float4(acc[i][0], acc[i][1], acc[i][2], acc[i][3]);
        *(float4*)(dst + 4) = make_float4(acc[i][4], acc[i][5], acc[i][6], acc[i][7]);
    }
}

// ---------------------------------------------------------------------------
__global__ __launch_bounds__(256) void final_reduce_k(const float* __restrict__ part,
                                                      const float* __restrict__ b1p,
                                                      const float* __restrict__ W2p,
                                                      const float* __restrict__ b2p,
                                                      float* __restrict__ raw) {
    constexpr int M = Bn * Nn;
    int wave = threadIdx.x >> 6, lane = threadIdx.x & 63;
    int row = blockIdx.x * 4 + wave;
    if (row >= M) return;
    float v0 = 0.f, v1 = 0.f;
#pragma unroll
    for (int s = 0; s < 4; ++s) {
        const float* pr = part + ((size_t)s * M + row) * 128;
        v0 += pr[lane];
        v1 += pr[lane + 64];
    }
    float p = tanhf(v0 + b1p[lane]) * W2p[lane] + tanhf(v1 + b1p[lane + 64]) * W2p[lane + 64];
    for (int off = 32; off; off >>= 1) p += __shfl_xor(p, off, 64);
    if (lane == 0) raw[row] = p + b2p[0];
}

// ---------------------------------------------------------------------------
__global__ __launch_bounds__(256) void predmax_k(const int* __restrict__ mask,
                                                 const float* __restrict__ raw,
                                                 float* __restrict__ out) {
    int idx = blockIdx.x * 4 + (threadIdx.x >> 6);
    int lane = threadIdx.x & 63;
    if (idx >= Bn * NCn) return;
    int b = idx / NCn, c = idx - b * NCn;
    const int* mrow = mask + ((size_t)b * NCn + c) * Nn;
    const float* rrow = raw + (size_t)b * Nn;
    float mx = -INFINITY;
    for (int n = lane; n < Nn; n += 64) {
        float v = mrow[n] ? rrow[n] : 0.0f;
        if (v == 0.0f) v = -1.0e6f;
        mx = fmaxf(mx, v);
    }
    for (int off = 32; off; off >>= 1) mx = fmaxf(mx, __shfl_xor(mx, off, 64));
    if (lane == 0) out[idx] = mx;
}

}  // namespace

extern "C" void kernel_launch(void* const* d_in, const int* in_sizes, int n_in,
                              void* d_out, int out_size, void* d_ws, size_t ws_size,
                              hipStream_t stream) {
    const float* nodes_glove  = (const float*)d_in[0];
    const float* query_glove  = (const float*)d_in[1];
    const float* adj          = (const float*)d_in[2];
    const int*   nodes_length = (const int*)d_in[3];
    const int*   maskp        = (const int*)d_in[4];
    const float* Wn = (const float*)d_in[5];
    const float* bn = (const float*)d_in[6];
    const float* Wq = (const float*)d_in[7];
    const float* bq = (const float*)d_in[8];
    const float* Wh = (const float*)d_in[9];
    const float* bh = (const float*)d_in[10];
    const float* Wc = (const float*)d_in[11];
    const float* bc = (const float*)d_in[12];
    const float* wa = (const float*)d_in[13];
    const float* W1 = (const float*)d_in[14];
    const float* b1 = (const float*)d_in[15];
    const float* W2 = (const float*)d_in[16];
    const float* b2 = (const float*)d_in[17];
    float* out = (float*)d_out;

    float* ws = (float*)d_ws;
    size_t off = 0;
    auto alloc = [&](size_t n) { float* p = ws + off; off += n; return p; };
    constexpr size_t ME = (size_t)Bn * Nn * ENC;   // 2,048,000
    float* nc   = alloc(ME);
    float* lh0  = alloc(ME);
    float* upd  = alloc(ME);          // reused as 4-seg split-K part buffer
    float* lh1  = alloc(ME);
    float* Asum = alloc(ME);          // [8][500][512] padded; reused as n2q
    float* qc   = alloc((size_t)Bn * Qn * ENC);
    float* rowmax = alloc(Bn * Nn);
    float* bvec   = alloc(Bn * Nn);
    float* q2n    = alloc(Bn * ENC);
    float* raw    = alloc(Bn * Nn);
    unsigned short* hmT = (unsigned short*)alloc((size_t)Bn * ENC * 512 / 2);  // [8][512][512]
    unsigned short* WnT = (unsigned short*)alloc((size_t)ENC * 320 / 2);
    unsigned short* WqT = (unsigned short*)alloc((size_t)ENC * 320 / 2);
    unsigned short* WhT = (unsigned short*)alloc((size_t)ENC * ENC / 2);
    unsigned short* WcT = (unsigned short*)alloc((size_t)ENC * 2 * ENC / 2);
    alloc(16384);  // tail pad: staging may over-read past last buffer
    float* n2q  = Asum;
    float* part = upd;

    constexpr int M = Bn * Nn;  // 4000

    sum_adj_pad_k<<<dim3(Bn * Nn), 128, 0, stream>>>(adj, Asum);
    tcvt_k<<<dim3(16, 10), 256, 0, stream>>>(Wn, WnT, DIN, ENC, 320);
    tcvt_k<<<dim3(16, 10), 256, 0, stream>>>(Wq, WqT, DIN, ENC, 320);
    tcvt_k<<<dim3(16, 16), 256, 0, stream>>>(Wh, WhT, ENC, ENC, ENC);
    tcvt_k<<<dim3(16, 32), 256, 0, stream>>>(Wc, WcT, 2 * ENC, ENC, 2 * ENC);

    gemm_nc_k<<<dim3((M + 63) / 64, 8), 256, 0, stream>>>(nodes_glove, WnT, bn,
                                                          nodes_length, nc, lh0);
    gemm_qc_k<<<dim3((Bn * Qn + 63) / 64, 8), 256, 0, stream>>>(query_glove, WqT, bq, qc);

    float* cur = lh0;
    float* nxt = lh1;
    for (int h = 0; h < 3; ++h) {
        gemm_hm_k<<<dim3((M + 63) / 64, 8), 256, 0, stream>>>(cur, WhT, bh,
                                                              nodes_length, hmT);
        gemm_upd_k<<<dim3(8, 8, Bn), 256, 0, stream>>>(Asum, hmT, upd);
        gemm_att_k<<<dim3((M + 63) / 64, 8), 256, 0, stream>>>(upd, cur, WcT, bc,
                                                               nodes_length, nxt);
        float* tmp = cur; cur = nxt; nxt = tmp;
    }
    // cur == lh1 == final last_hop; Asum & upd now free.

    sim_fused_k<<<dim3(Bn, 125), 256, 0, stream>>>(cur, qc, wa, n2q, rowmax);
    bvec_k<<<dim3(Bn), 512, 0, stream>>>(rowmax, bvec);
    q2n_k<<<dim3(Bn, ENC / 256), 256, 0, stream>>>(bvec, nc, q2n);
    final_part_k<<<dim3((M + 63) / 64, 4), 256, 0, stream>>>(nc, n2q, q2n, W1, part);
    final_reduce_k<<<dim3((M + 3) / 4), 256, 0, stream>>>(part, b1, W2, b2, raw);
    predmax_k<<<dim3((Bn * NCn + 3) / 4), 256, 0, stream>>>(maskp, raw, out);
}

// Round 7
// 464.500 us; speedup vs baseline: 2.2689x; 1.0536x over previous
//
#include <hip/hip_runtime.h>
#include <math.h>
#include <stdint.h>

namespace {

constexpr int Bn  = 8;
constexpr int Nn  = 500;
constexpr int Qn  = 25;
constexpr int ENC = 512;
constexpr int DIN = 300;
constexpr int NCn = 70;
constexpr int NETn = 3;

typedef __attribute__((ext_vector_type(8))) short bf16x8_t;
typedef __attribute__((ext_vector_type(4))) float f32x4_t;

__device__ __forceinline__ unsigned short f2bf(float f) {
    unsigned int u = __builtin_bit_cast(unsigned int, f);
    u += 0x7fffu + ((u >> 16) & 1u);   // RNE
    return (unsigned short)(u >> 16);
}
__device__ __forceinline__ float bf2f(unsigned short h) {
    unsigned int u = ((unsigned int)h) << 16;
    return __builtin_bit_cast(float, u);
}
__device__ __forceinline__ float sigmoidf_(float x) { return 1.0f / (1.0f + expf(-x)); }

// ---------------------------------------------------------------------------
// Asum[b][i][j] = sum_e adj[b,e,i,j], fp32, j padded 500->512 with zeros.
__global__ __launch_bounds__(128) void sum_adj_pad_k(const float* __restrict__ adj,
                                                     float* __restrict__ Asum) {
    int bi = blockIdx.x;
    int b = bi / Nn, i = bi - b * Nn;
    int j = threadIdx.x * 4;
    float4 s = make_float4(0.f, 0.f, 0.f, 0.f);
    if (j < Nn) {
#pragma unroll
        for (int e = 0; e < NETn; ++e) {
            const float* p = adj + (((size_t)(b * NETn + e) * Nn) + i) * Nn + j;
            float4 v = *(const float4*)p;
            s.x += v.x; s.y += v.y; s.z += v.z; s.w += v.w;
        }
    }
    *(float4*)(Asum + ((size_t)bi) * 512 + j) = s;
}

// ---------------------------------------------------------------------------
// Transpose + convert: in f32 [K][N] -> out bf16 [N][Kpad], zero-padded k>=K.
__global__ __launch_bounds__(256) void tcvt_k(const float* __restrict__ in,
                                              unsigned short* __restrict__ out,
                                              int K, int N, int Kpad) {
    __shared__ float tile[32][33];
    int tx = threadIdx.x & 31, ty = threadIdx.x >> 5;
    int n0 = blockIdx.x * 32, k0 = blockIdx.y * 32;
#pragma unroll
    for (int r = 0; r < 4; ++r) {
        int k = k0 + ty * 4 + r;
        int n = n0 + tx;
        tile[ty * 4 + r][tx] = (k < K && n < N) ? in[(size_t)k * N + n] : 0.0f;
    }
    __syncthreads();
#pragma unroll
    for (int r = 0; r < 4; ++r) {
        int n = n0 + ty * 4 + r;
        int k = k0 + tx;
        if (n < N && k < Kpad) out[(size_t)n * Kpad + k] = f2bf(tile[tx][ty * 4 + r]);
    }
}

// ---------------------------------------------------------------------------
// MFMA core (R4-proven): 64x64 tile, BK=32, 4 waves (2x2 of 32x32),
// double-buffered LDS, one barrier per 32-k step.
// A fp32 row-major (optional A2 concat for k>=ksplit); boundary k-chunks clamp
// loads at Klim (beyond-K values multiply zero-padded B rows -> no effect).
// Bt: bf16 B^T row-major [n][k]. LDS 16B lines XOR-swizzled (conflict-free).
__device__ __forceinline__ void mfma_core(
    const float* __restrict__ A, const float* __restrict__ A2,
    int lda, int ksplit, int Klim,
    const unsigned short* __restrict__ Bt, int ldb,
    int m0, int n0, int K, int Mlim,
    unsigned short* As, unsigned short* Bts, f32x4_t acc[2][2]) {
    const int t = threadIdx.x;
    const int lane = t & 63;
    const int w = t >> 6;
    const int sm = t >> 2;                 // staging row 0..63
    const int sp = t & 3;                  // physical 16B line within row
    const int sq = sp ^ ((sm >> 1) & 3);   // logical k-chunk staged
    const int arow = m0 + sm;
    const bool rowok = arow < Mlim;
    const int wm = (w & 1) * 32, wn = (w >> 1) * 32;
    const int quad = lane >> 4, cidx = lane & 15;
    const int am0 = wm + cidx, am1 = wm + 16 + cidx;
    const int an0 = wn + cidx, an1 = wn + 16 + cidx;
    const int apo0 = am0 * 32 + (quad ^ ((am0 >> 1) & 3)) * 8;
    const int apo1 = am1 * 32 + (quad ^ ((am1 >> 1) & 3)) * 8;
    const int bpo0 = an0 * 32 + (quad ^ ((an0 >> 1) & 3)) * 8;
    const int bpo1 = an1 * 32 + (quad ^ ((an1 >> 1) & 3)) * 8;

    bf16x8_t ast, bst;
    auto stage = [&](int k0) {
        int kg = k0 + sq * 8;
        float4 f0 = make_float4(0.f, 0.f, 0.f, 0.f);
        float4 f1 = make_float4(0.f, 0.f, 0.f, 0.f);
        if (rowok) {
            const float* src = (A2 != nullptr && kg >= ksplit)
                                   ? A2 + (size_t)arow * lda + (kg - ksplit)
                                   : A + (size_t)arow * lda + kg;
            if (kg + 8 <= Klim) {
                f0 = *(const float4*)src;
                f1 = *(const float4*)(src + 4);
            } else if (kg + 4 <= Klim) {
                f0 = *(const float4*)src;
            }
        }
        bst = *(const bf16x8_t*)(Bt + (size_t)(n0 + sm) * ldb + kg);
        ast[0] = (short)f2bf(f0.x); ast[1] = (short)f2bf(f0.y);
        ast[2] = (short)f2bf(f0.z); ast[3] = (short)f2bf(f0.w);
        ast[4] = (short)f2bf(f1.x); ast[5] = (short)f2bf(f1.y);
        ast[6] = (short)f2bf(f1.z); ast[7] = (short)f2bf(f1.w);
    };

    const int ktot = K >> 5;
    stage(0);
    *(bf16x8_t*)(As + t * 8) = ast;
    *(bf16x8_t*)(Bts + t * 8) = bst;
    for (int kt = 0; kt < ktot; ++kt) {
        __syncthreads();
        const int cur = (kt & 1) * 2048;
        const bool more = (kt + 1) < ktot;
        if (more) stage((kt + 1) << 5);
        bf16x8_t a0 = *(const bf16x8_t*)(As + cur + apo0);
        bf16x8_t a1 = *(const bf16x8_t*)(As + cur + apo1);
        bf16x8_t b0 = *(const bf16x8_t*)(Bts + cur + bpo0);
        bf16x8_t b1 = *(const bf16x8_t*)(Bts + cur + bpo1);
        acc[0][0] = __builtin_amdgcn_mfma_f32_16x16x32_bf16(a0, b0, acc[0][0], 0, 0, 0);
        acc[0][1] = __builtin_amdgcn_mfma_f32_16x16x32_bf16(a0, b1, acc[0][1], 0, 0, 0);
        acc[1][0] = __builtin_amdgcn_mfma_f32_16x16x32_bf16(a1, b0, acc[1][0], 0, 0, 0);
        acc[1][1] = __builtin_amdgcn_mfma_f32_16x16x32_bf16(a1, b1, acc[1][1], 0, 0, 0);
        if (more) {
            const int nxt = ((kt + 1) & 1) * 2048;
            *(bf16x8_t*)(As + nxt + t * 8) = ast;
            *(bf16x8_t*)(Bts + nxt + t * 8) = bst;
        }
    }
}

#define EPI_SETUP                                         \
    int t = threadIdx.x, lane = t & 63, w = t >> 6;       \
    int wm = (w & 1) * 32, wn = (w >> 1) * 32;            \
    int quad = lane >> 4, cidx = lane & 15;               \
    (void)wm; (void)wn; (void)quad; (void)cidx;

// ---------------------------------------------------------------------------
__global__ __launch_bounds__(256) void gemm_nc_k(const float* __restrict__ ng,
                                                 const unsigned short* __restrict__ WnT,
                                                 const float* __restrict__ bn,
                                                 const int* __restrict__ lens,
                                                 float* __restrict__ nc,
                                                 float* __restrict__ lh0) {
    __shared__ __align__(16) unsigned short As[4096], Bts[4096];
    f32x4_t z = {0.f, 0.f, 0.f, 0.f};
    f32x4_t acc[2][2] = {{z, z}, {z, z}};
    int m0 = blockIdx.x * 64, n0 = blockIdx.y * 64;
    mfma_core(ng, nullptr, DIN, 1 << 30, DIN, WnT, 320, m0, n0, 320, Bn * Nn, As, Bts, acc);
    EPI_SETUP
#pragma unroll
    for (int nj = 0; nj < 2; ++nj) {
        int col = n0 + wn + nj * 16 + cidx;
        float bias = bn[col];
#pragma unroll
        for (int mi = 0; mi < 2; ++mi) {
#pragma unroll
            for (int r = 0; r < 4; ++r) {
                int row = m0 + wm + mi * 16 + quad * 4 + r;
                if (row < Bn * Nn) {
                    float tv = tanhf(acc[mi][nj][r] + bias);
                    int b = row / Nn, i = row - b * Nn;
                    float rm = (i < lens[b]) ? 1.0f : 0.0f;
                    nc[(size_t)row * ENC + col] = tv;
                    lh0[(size_t)row * ENC + col] = tv * rm;
                }
            }
        }
    }
}

// ---------------------------------------------------------------------------
__global__ __launch_bounds__(256) void gemm_qc_k(const float* __restrict__ qg,
                                                 const unsigned short* __restrict__ WqT,
                                                 const float* __restrict__ bq,
                                                 float* __restrict__ qc) {
    __shared__ __align__(16) unsigned short As[4096], Bts[4096];
    f32x4_t z = {0.f, 0.f, 0.f, 0.f};
    f32x4_t acc[2][2] = {{z, z}, {z, z}};
    int m0 = blockIdx.x * 64, n0 = blockIdx.y * 64;
    mfma_core(qg, nullptr, DIN, 1 << 30, DIN, WqT, 320, m0, n0, 320, Bn * Qn, As, Bts, acc);
    EPI_SETUP
#pragma unroll
    for (int nj = 0; nj < 2; ++nj) {
        int col = n0 + wn + nj * 16 + cidx;
        float bias = bq[col];
#pragma unroll
        for (int mi = 0; mi < 2; ++mi) {
#pragma unroll
            for (int r = 0; r < 4; ++r) {
                int row = m0 + wm + mi * 16 + quad * 4 + r;
                if (row < Bn * Qn) qc[(size_t)row * ENC + col] = acc[mi][nj][r] + bias;
            }
        }
    }
}

// ---------------------------------------------------------------------------
__global__ __launch_bounds__(256) void gemm_hm_k(const float* __restrict__ lh,
                                                 const unsigned short* __restrict__ WhT,
                                                 const float* __restrict__ bh,
                                                 const int* __restrict__ lens,
                                                 unsigned short* __restrict__ hmT) {
    __shared__ __align__(16) unsigned short As[4096], Bts[4096];
    f32x4_t z = {0.f, 0.f, 0.f, 0.f};
    f32x4_t acc[2][2] = {{z, z}, {z, z}};
    int m0 = blockIdx.x * 64, n0 = blockIdx.y * 64;
    mfma_core(lh, nullptr, ENC, 1 << 30, ENC, WhT, ENC, m0, n0, ENC, Bn * Nn, As, Bts, acc);
    EPI_SETUP
#pragma unroll
    for (int nj = 0; nj < 2; ++nj) {
        int col = n0 + wn + nj * 16 + cidx;
        float bias = bh[col];
#pragma unroll
        for (int mi = 0; mi < 2; ++mi) {
#pragma unroll
            for (int r = 0; r < 4; ++r) {
                int row = m0 + wm + mi * 16 + quad * 4 + r;
                if (row < Bn * Nn) {
                    int b = row / Nn, i = row - b * Nn;
                    float rm = (i < lens[b]) ? 1.0f : 0.0f;
                    float v = (acc[mi][nj][r] + bias) * rm;
                    hmT[((size_t)b * ENC + col) * 512 + i] = f2bf(v);
                }
            }
        }
    }
}

// ---------------------------------------------------------------------------
// upd = Asum[b] @ hm[b] + hm[b]   (A fp32 padded [500][512], batched via z)
__global__ __launch_bounds__(256) void gemm_upd_k(const float* __restrict__ Asum,
                                                  const unsigned short* __restrict__ hmT,
                                                  float* __restrict__ upd) {
    __shared__ __align__(16) unsigned short As[4096], Bts[4096];
    f32x4_t z = {0.f, 0.f, 0.f, 0.f};
    f32x4_t acc[2][2] = {{z, z}, {z, z}};
    int b = blockIdx.z;
    const float* A = Asum + (size_t)b * Nn * 512;
    const unsigned short* BtH = hmT + (size_t)b * ENC * 512;
    int m0 = blockIdx.x * 64, n0 = blockIdx.y * 64;
    mfma_core(A, nullptr, 512, 1 << 30, 512, BtH, 512, m0, n0, 512, Nn, As, Bts, acc);
    EPI_SETUP
#pragma unroll
    for (int nj = 0; nj < 2; ++nj) {
        int col = n0 + wn + nj * 16 + cidx;
#pragma unroll
        for (int mi = 0; mi < 2; ++mi) {
#pragma unroll
            for (int r = 0; r < 4; ++r) {
                int i = m0 + wm + mi * 16 + quad * 4 + r;
                if (i < Nn) {
                    float hv = bf2f(hmT[((size_t)b * ENC + col) * 512 + i]);
                    upd[((size_t)(b * Nn + i)) * ENC + col] = acc[mi][nj][r] + hv;
                }
            }
        }
    }
}

// ---------------------------------------------------------------------------
__global__ __launch_bounds__(256) void gemm_att_k(const float* __restrict__ upd,
                                                  const float* __restrict__ lh,
                                                  const unsigned short* __restrict__ WcT,
                                                  const float* __restrict__ bc,
                                                  const int* __restrict__ lens,
                                                  float* __restrict__ lh_out) {
    __shared__ __align__(16) unsigned short As[4096], Bts[4096];
    f32x4_t z = {0.f, 0.f, 0.f, 0.f};
    f32x4_t acc[2][2] = {{z, z}, {z, z}};
    int m0 = blockIdx.x * 64, n0 = blockIdx.y * 64;
    mfma_core(upd, lh, ENC, ENC, 1 << 30, WcT, 2 * ENC, m0, n0, 2 * ENC, Bn * Nn, As, Bts, acc);
    EPI_SETUP
#pragma unroll
    for (int nj = 0; nj < 2; ++nj) {
        int col = n0 + wn + nj * 16 + cidx;
        float bias = bc[col];
#pragma unroll
        for (int mi = 0; mi < 2; ++mi) {
#pragma unroll
            for (int r = 0; r < 4; ++r) {
                int row = m0 + wm + mi * 16 + quad * 4 + r;
                if (row < Bn * Nn) {
                    int b = row / Nn, i = row - b * Nn;
                    float rm = (i < lens[b]) ? 1.0f : 0.0f;
                    float a = sigmoidf_(acc[mi][nj][r] + bias) * rm;
                    size_t off = (size_t)row * ENC + col;
                    lh_out[off] = a * tanhf(upd[off]) + (1.0f - a) * lh[off];
                }
            }
        }
    }
}

// ---------------------------------------------------------------------------
// Fused sim -> softmax(q) -> nodes2query + rowmax.  One wave per n-row.
__global__ __launch_bounds__(256) void sim_fused_k(const float* __restrict__ lh,
                                                   const float* __restrict__ qc,
                                                   const float* __restrict__ wa,
                                                   float* __restrict__ n2q,
                                                   float* __restrict__ rowmax) {
    __shared__ float qcs[Qn * ENC];   // 51.2 KB
    __shared__ float qdot[32];
    int b = blockIdx.x;
    int t = threadIdx.x;
    const float* qcb = qc + (size_t)b * Qn * ENC;
    for (int i = t * 4; i < Qn * ENC; i += 1024) *(float4*)&qcs[i] = *(const float4*)&qcb[i];
    __syncthreads();
    {
        int q = t >> 3, j = t & 7;
        if (q < Qn) {
            float s = 0.f;
            for (int k = 0; k < 64; ++k) {
                int d = j + 8 * k;
                s += qcs[q * ENC + d] * wa[ENC + d];
            }
            s += __shfl_xor(s, 1, 64);
            s += __shfl_xor(s, 2, 64);
            s += __shfl_xor(s, 4, 64);
            if (j == 0) qdot[q] = s;
        }
    }
    __syncthreads();

    int wv = t >> 6, lane = t & 63;
    int n = blockIdx.y * 4 + wv;
    int d0 = lane * 8;
    const float* lrow = lh + ((size_t)b * Nn + n) * ENC;
    float4 la = *(const float4*)(lrow + d0);
    float4 lb = *(const float4*)(lrow + d0 + 4);
    float lv[8] = {la.x, la.y, la.z, la.w, lb.x, lb.y, lb.z, lb.w};
    float ndp = 0.f;
    float lvs[8];
#pragma unroll
    for (int j = 0; j < 8; ++j) {
        ndp += lv[j] * wa[d0 + j];
        lvs[j] = lv[j] * wa[2 * ENC + d0 + j];
    }
#pragma unroll
    for (int off = 32; off; off >>= 1) ndp += __shfl_xor(ndp, off, 64);

    float s_[Qn];
#pragma unroll
    for (int q = 0; q < Qn; ++q) {
        const float* qrow = qcs + q * ENC + d0;
        float4 qa = *(const float4*)qrow;
        float4 qb = *(const float4*)(qrow + 4);
        s_[q] = lvs[0] * qa.x + lvs[1] * qa.y + lvs[2] * qa.z + lvs[3] * qa.w +
                lvs[4] * qb.x + lvs[5] * qb.y + lvs[6] * qb.z + lvs[7] * qb.w;
    }
#pragma unroll
    for (int q = 0; q < Qn; ++q) {
#pragma unroll
        for (int off = 32; off; off >>= 1) s_[q] += __shfl_xor(s_[q], off, 64);
    }
    float mx = -INFINITY;
#pragma unroll
    for (int q = 0; q < Qn; ++q) {
        s_[q] += ndp + qdot[q];
        mx = fmaxf(mx, s_[q]);
    }
    float sum = 0.f;
#pragma unroll
    for (int q = 0; q < Qn; ++q) { s_[q] = expf(s_[q] - mx); sum += s_[q]; }
    float inv = 1.0f / sum;
    float o[8] = {};
#pragma unroll
    for (int q = 0; q < Qn; ++q) {
        const float* qrow = qcs + q * ENC + d0;
        float4 qa = *(const float4*)qrow;
        float4 qb = *(const float4*)(qrow + 4);
        float p = s_[q] * inv;
        o[0] += p * qa.x; o[1] += p * qa.y; o[2] += p * qa.z; o[3] += p * qa.w;
        o[4] += p * qb.x; o[5] += p * qb.y; o[6] += p * qb.z; o[7] += p * qb.w;
    }
    float* orow = n2q + ((size_t)b * Nn + n) * ENC + d0;
    *(float4*)orow = make_float4(o[0], o[1], o[2], o[3]);
    *(float4*)(orow + 4) = make_float4(o[4], o[5], o[6], o[7]);
    if (lane == 0) rowmax[b * Nn + n] = mx;
}

// ---------------------------------------------------------------------------
__global__ __launch_bounds__(512) void bvec_k(const float* __restrict__ rowmax,
                                              float* __restrict__ bvec) {
    __shared__ float red[8];
    int b = blockIdx.x, t = threadIdx.x;
    float v = (t < Nn) ? rowmax[b * Nn + t] : -INFINITY;
    float m = v;
    for (int off = 32; off; off >>= 1) m = fmaxf(m, __shfl_xor(m, off, 64));
    if ((t & 63) == 0) red[t >> 6] = m;
    __syncthreads();
    float bm = red[0];
    for (int i = 1; i < 8; ++i) bm = fmaxf(bm, red[i]);
    float e = (t < Nn) ? expf(v - bm) : 0.0f;
    float ssum = e;
    for (int off = 32; off; off >>= 1) ssum += __shfl_xor(ssum, off, 64);
    __syncthreads();
    if ((t & 63) == 0) red[t >> 6] = ssum;
    __syncthreads();
    float tot = 0.f;
    for (int i = 0; i < 8; ++i) tot += red[i];
    if (t < Nn) bvec[b * Nn + t] = e / tot;
}

// ---------------------------------------------------------------------------
__global__ __launch_bounds__(256) void q2n_k(const float* __restrict__ bvec,
                                             const float* __restrict__ nc,
                                             float* __restrict__ q2n) {
    int b = blockIdx.x;
    int d = blockIdx.y * 256 + threadIdx.x;
    const float* ncb = nc + (size_t)b * Nn * ENC;
    float acc = 0.f;
    for (int n = 0; n < Nn; ++n) acc = fmaf(bvec[b * Nn + n], ncb[(size_t)n * ENC + d], acc);
    q2n[b * ENC + d] = acc;
}

// ---------------------------------------------------------------------------
// Split-K partial of g @ W1: seg = blockIdx.y in [0,8), K-range seg*256..+256.
// g = [nc | n2q | nc*n2q | nc*q2n]; each seg lies inside one 512-wide part.
// (R2-proven kernel.)
__global__ __launch_bounds__(256) void final_part_k(const float* __restrict__ nc,
                                                    const float* __restrict__ n2q,
                                                    const float* __restrict__ q2n,
                                                    const float* __restrict__ W1p,
                                                    float* __restrict__ part) {
    __shared__ float As[16][68];
    __shared__ float W1s[16][128];
    int t = threadIdx.x;
    int m0 = blockIdx.x * 64;
    int seg = blockIdx.y;          // 0..7
    int p = seg >> 1;
    int dbase = (seg & 1) * 256;
    int tmr = t & 15;
    int tnc = t >> 4;
    int la_r = t >> 2;             // 0..63
    int la_k = (t & 3) * 4;
    constexpr int M = Bn * Nn;

    float acc[4][8] = {};
    for (int kt = 0; kt < 16; ++kt) {
        int k0 = kt << 4;
        {
            int row = m0 + la_r;
            int d = dbase + k0 + la_k;
            float4 v = make_float4(0.f, 0.f, 0.f, 0.f);
            if (row < M) {
                size_t off = (size_t)row * ENC + d;
                if (p == 0) v = *(const float4*)(nc + off);
                else if (p == 1) v = *(const float4*)(n2q + off);
                else if (p == 2) {
                    float4 a = *(const float4*)(nc + off);
                    float4 c = *(const float4*)(n2q + off);
                    v = make_float4(a.x * c.x, a.y * c.y, a.z * c.z, a.w * c.w);
                } else {
                    int bidx = row / Nn;
                    float4 a = *(const float4*)(nc + off);
                    float4 qv = *(const float4*)(q2n + (size_t)bidx * ENC + d);
                    v = make_float4(a.x * qv.x, a.y * qv.y, a.z * qv.z, a.w * qv.w);
                }
            }
            As[la_k + 0][la_r] = v.x; As[la_k + 1][la_r] = v.y;
            As[la_k + 2][la_r] = v.z; As[la_k + 3][la_r] = v.w;
        }
#pragma unroll
        for (int r = 0; r < 2; ++r) {
            int idx = t + r * 256;
            int kr = idx >> 5;
            int nq = (idx & 31) * 4;
            *(float4*)&W1s[kr][nq] =
                *(const float4*)(W1p + (size_t)(seg * 256 + k0 + kr) * 128 + nq);
        }
        __syncthreads();
#pragma unroll
        for (int kk = 0; kk < 16; ++kk) {
            float4 av = *(const float4*)&As[kk][tmr * 4];
            float4 b0 = *(const float4*)&W1s[kk][tnc * 8];
            float4 b1v = *(const float4*)&W1s[kk][tnc * 8 + 4];
            float a_[4] = {av.x, av.y, av.z, av.w};
            float b_[8] = {b0.x, b0.y, b0.z, b0.w, b1v.x, b1v.y, b1v.z, b1v.w};
#pragma unroll
            for (int i = 0; i < 4; ++i)
#pragma unroll
                for (int j = 0; j < 8; ++j) acc[i][j] = fmaf(a_[i], b_[j], acc[i][j]);
        }
        __syncthreads();
    }
    for (int i = 0; i < 4; ++i) {
        int row = m0 + tmr * 4 + i;
        if (row >= M) break;
        float* dst = part + ((size_t)seg * M + row) * 128 + tnc * 8;
        *(float4*)dst = make_float4(acc[i][0], acc[i][1], acc[i][2], acc[i][3]);
        *(float4*)(dst + 4) = make_float4(acc[i][4], acc[i][5], acc[i][6], acc[i][7]);
    }
}

// ---------------------------------------------------------------------------
// raw[row] = b2 + sum_h tanh(sum_s part[s][row][h] + b1[h]) * W2[h]
__global__ __launch_bounds__(256) void final_reduce_k(const float* __restrict__ part,
                                                      const float* __restrict__ b1p,
                                                      const float* __restrict__ W2p,
                                                      const float* __restrict__ b2p,
                                                      float* __restrict__ raw) {
    constexpr int M = Bn * Nn;
    int wave = threadIdx.x >> 6, lane = threadIdx.x & 63;
    int row = blockIdx.x * 4 + wave;
    if (row >= M) return;
    float v0 = 0.f, v1 = 0.f;
#pragma unroll
    for (int s = 0; s < 8; ++s) {
        const float* pr = part + ((size_t)s * M + row) * 128;
        v0 += pr[lane];
        v1 += pr[lane + 64];
    }
    float p = tanhf(v0 + b1p[lane]) * W2p[lane] + tanhf(v1 + b1p[lane + 64]) * W2p[lane + 64];
    for (int off = 32; off; off >>= 1) p += __shfl_xor(p, off, 64);
    if (lane == 0) raw[row] = p + b2p[0];
}

// ---------------------------------------------------------------------------
__global__ __launch_bounds__(256) void predmax_k(const int* __restrict__ mask,
                                                 const float* __restrict__ raw,
                                                 float* __restrict__ out) {
    int idx = blockIdx.x * 4 + (threadIdx.x >> 6);
    int lane = threadIdx.x & 63;
    if (idx >= Bn * NCn) return;
    int b = idx / NCn, c = idx - b * NCn;
    const int* mrow = mask + ((size_t)b * NCn + c) * Nn;
    const float* rrow = raw + (size_t)b * Nn;
    float mx = -INFINITY;
    for (int n = lane; n < Nn; n += 64) {
        float v = mrow[n] ? rrow[n] : 0.0f;
        if (v == 0.0f) v = -1.0e6f;
        mx = fmaxf(mx, v);
    }
    for (int off = 32; off; off >>= 1) mx = fmaxf(mx, __shfl_xor(mx, off, 64));
    if (lane == 0) out[idx] = mx;
}

}  // namespace

extern "C" void kernel_launch(void* const* d_in, const int* in_sizes, int n_in,
                              void* d_out, int out_size, void* d_ws, size_t ws_size,
                              hipStream_t stream) {
    const float* nodes_glove  = (const float*)d_in[0];
    const float* query_glove  = (const float*)d_in[1];
    const float* adj          = (const float*)d_in[2];
    const int*   nodes_length = (const int*)d_in[3];
    const int*   maskp        = (const int*)d_in[4];
    const float* Wn = (const float*)d_in[5];
    const float* bn = (const float*)d_in[6];
    const float* Wq = (const float*)d_in[7];
    const float* bq = (const float*)d_in[8];
    const float* Wh = (const float*)d_in[9];
    const float* bh = (const float*)d_in[10];
    const float* Wc = (const float*)d_in[11];
    const float* bc = (const float*)d_in[12];
    const float* wa = (const float*)d_in[13];
    const float* W1 = (const float*)d_in[14];
    const float* b1 = (const float*)d_in[15];
    const float* W2 = (const float*)d_in[16];
    const float* b2 = (const float*)d_in[17];
    float* out = (float*)d_out;

    float* ws = (float*)d_ws;
    size_t off = 0;
    auto alloc = [&](size_t n) { float* p = ws + off; off += n; return p; };
    constexpr size_t ME = (size_t)Bn * Nn * ENC;   // 2,048,000
    // lh0 and upd must be ADJACENT: they become the 8-seg split-K part buffer
    // (8*4000*128 = 4,096,000 floats) after the hops.
    float* nc   = alloc(ME);
    float* lh0  = alloc(ME);
    float* upd  = alloc(ME);
    float* lh1  = alloc(ME);
    float* Asum = alloc(ME);          // fp32 [8][500][512]; reused as n2q later
    float* qc   = alloc((size_t)Bn * Qn * ENC);
    float* rowmax = alloc(Bn * Nn);
    float* bvec   = alloc(Bn * Nn);
    float* q2n    = alloc(Bn * ENC);
    float* raw    = alloc(Bn * Nn);
    unsigned short* hmT = (unsigned short*)alloc((size_t)Bn * ENC * 512 / 2);
    unsigned short* WnT = (unsigned short*)alloc((size_t)ENC * 320 / 2);
    unsigned short* WqT = (unsigned short*)alloc((size_t)ENC * 320 / 2);
    unsigned short* WhT = (unsigned short*)alloc((size_t)ENC * ENC / 2);
    unsigned short* WcT = (unsigned short*)alloc((size_t)ENC * 2 * ENC / 2);
    alloc(16384);  // tail pad
    float* n2q  = Asum;               // reused after hops
    float* part = lh0;                // spans lh0 + upd after hops

    constexpr int M = Bn * Nn;  // 4000

    sum_adj_pad_k<<<dim3(Bn * Nn), 128, 0, stream>>>(adj, Asum);
    tcvt_k<<<dim3(16, 10), 256, 0, stream>>>(Wn, WnT, DIN, ENC, 320);
    tcvt_k<<<dim3(16, 10), 256, 0, stream>>>(Wq, WqT, DIN, ENC, 320);
    tcvt_k<<<dim3(16, 16), 256, 0, stream>>>(Wh, WhT, ENC, ENC, ENC);
    tcvt_k<<<dim3(16, 32), 256, 0, stream>>>(Wc, WcT, 2 * ENC, ENC, 2 * ENC);

    gemm_nc_k<<<dim3((M + 63) / 64, 8), 256, 0, stream>>>(nodes_glove, WnT, bn,
                                                          nodes_length, nc, lh0);
    gemm_qc_k<<<dim3((Bn * Qn + 63) / 64, 8), 256, 0, stream>>>(query_glove, WqT, bq, qc);

    // 3 hops; cur starts at lh0 so after 3 swaps cur==lh1, freeing lh0+upd.
    float* cur = lh0;
    float* nxt = lh1;
    for (int h = 0; h < 3; ++h) {
        gemm_hm_k<<<dim3((M + 63) / 64, 8), 256, 0, stream>>>(cur, WhT, bh,
                                                              nodes_length, hmT);
        gemm_upd_k<<<dim3(8, 8, Bn), 256, 0, stream>>>(Asum, hmT, upd);
        gemm_att_k<<<dim3((M + 63) / 64, 8), 256, 0, stream>>>(upd, cur, WcT, bc,
                                                               nodes_length, nxt);
        float* tmp = cur; cur = nxt; nxt = tmp;
    }
    // cur == lh1 == final last_hop; lh0, upd, Asum now free.

    sim_fused_k<<<dim3(Bn, 125), 256, 0, stream>>>(cur, qc, wa, n2q, rowmax);
    bvec_k<<<dim3(Bn), 512, 0, stream>>>(rowmax, bvec);
    q2n_k<<<dim3(Bn, ENC / 256), 256, 0, stream>>>(bvec, nc, q2n);
    final_part_k<<<dim3((M + 63) / 64, 8), 256, 0, stream>>>(nc, n2q, q2n, W1, part);
    final_reduce_k<<<dim3((M + 3) / 4), 256, 0, stream>>>(part, b1, W2, b2, raw);
    predmax_k<<<dim3((Bn * NCn + 3) / 4), 256, 0, stream>>>(maskp, raw, out);
}